// Round 1
// baseline (475.022 us; speedup 1.0000x reference)
//
#include <hip/hip_runtime.h>
#include <hip/hip_bf16.h>
#include <math.h>

#define D_MODEL 768
#define NTOK    8192   // B*N
#define SEQ     1024
#define NH      12
#define DHD     64
#define DFF     3072

typedef __attribute__((ext_vector_type(8))) __bf16 bf16x8;
typedef __attribute__((ext_vector_type(4))) float  f32x4;
typedef __attribute__((ext_vector_type(4))) unsigned short us4;

typedef const __attribute__((address_space(1))) void g_void;
typedef __attribute__((address_space(3))) void lds_void;

__device__ __forceinline__ unsigned short f2bf(float f) {
  unsigned u = __float_as_uint(f);
  u += 0x7fffu + ((u >> 16) & 1u);   // RNE to bf16
  return (unsigned short)(u >> 16);
}

__device__ __forceinline__ f32x4 mfma16(bf16x8 a, bf16x8 b, f32x4 c) {
  return __builtin_amdgcn_mfma_f32_16x16x32_bf16(a, b, c, 0, 0, 0);
}

// async global->LDS, 16B per lane; LDS dest = uniform base + lane*16
__device__ __forceinline__ void gload_lds16(const unsigned short* g, unsigned short* l) {
  __builtin_amdgcn_global_load_lds((g_void*)g, (lds_void*)l, 16, 0, 0);
}

// ---------------- LayerNorm: one wave per row of 768, fp32 in -> bf16 out ----
__global__ __launch_bounds__(256)
void ln_kernel(const float* __restrict__ x, const float* __restrict__ gam,
               const float* __restrict__ bet, unsigned short* __restrict__ out) {
  const int w = threadIdx.x >> 6, lane = threadIdx.x & 63;
  const size_t row = (size_t)blockIdx.x * 4 + w;
  const float* xr = x + row * D_MODEL;
  f32x4 v[3];
#pragma unroll
  for (int c = 0; c < 3; ++c) v[c] = *(const f32x4*)(xr + c * 256 + lane * 4);
  float s = 0.f;
#pragma unroll
  for (int c = 0; c < 3; ++c)
#pragma unroll
    for (int j = 0; j < 4; ++j) s += v[c][j];
#pragma unroll
  for (int o = 32; o; o >>= 1) s += __shfl_xor(s, o);
  const float mu = s * (1.0f / D_MODEL);
  float vs = 0.f;
#pragma unroll
  for (int c = 0; c < 3; ++c)
#pragma unroll
    for (int j = 0; j < 4; ++j) { float d = v[c][j] - mu; vs += d * d; }
#pragma unroll
  for (int o = 32; o; o >>= 1) vs += __shfl_xor(vs, o);
  const float rs = rsqrtf(vs * (1.0f / D_MODEL) + 1e-5f);
  unsigned short* orow = out + row * D_MODEL;
#pragma unroll
  for (int c = 0; c < 3; ++c) {
    us4 o4;
#pragma unroll
    for (int j = 0; j < 4; ++j) {
      int idx = c * 256 + lane * 4 + j;
      o4[j] = f2bf((v[c][j] - mu) * rs * gam[idx] + bet[idx]);
    }
    *(us4*)(orow + c * 256 + lane * 4) = o4;
  }
}

// ------------- weight transpose + cast: W[K][Nc] f32 -> Wt[Nc][K] bf16 -------
__global__ __launch_bounds__(256)
void wtrans_kernel(const float* __restrict__ W, unsigned short* __restrict__ Wt,
                   int K, int Nc) {
  __shared__ float t[32][33];
  const int tx = threadIdx.x & 31, ty = threadIdx.x >> 5;  // 32x8
  const int nb = blockIdx.x * 32, kb = blockIdx.y * 32;
#pragma unroll
  for (int i = 0; i < 4; ++i)
    t[ty + 8 * i][tx] = W[(size_t)(kb + ty + 8 * i) * Nc + nb + tx];
  __syncthreads();
#pragma unroll
  for (int i = 0; i < 4; ++i)
    Wt[(size_t)(nb + ty + 8 * i) * K + kb + tx] = f2bf(t[tx][ty + 8 * i]);
}

// ---------------- GEMM: C[M][N] = A[M][K] @ Bt[N][K]^T, bf16 in, fused epilogue
#define MODE_QKV  0
#define MODE_PROJ 1
#define MODE_FFN1 2
#define MODE_FFN2 3

template <int MODE>
__global__ __launch_bounds__(256)
void gemm_bt(const unsigned short* __restrict__ A, const unsigned short* __restrict__ Bt,
             int K, const float* __restrict__ bias, const float* __restrict__ resid,
             float* __restrict__ outF, unsigned short* __restrict__ o0,
             unsigned short* __restrict__ o1, unsigned short* __restrict__ o2) {
  __shared__ alignas(16) unsigned short sA[2][128 * 32];
  __shared__ alignas(16) unsigned short sB[2][128 * 32];
  const int tid = threadIdx.x;
  const int w = tid >> 6, lane = tid & 63;
  const int lr = lane & 15, lg = lane >> 4;
  const int wm = w >> 1, wn = w & 1;
  const size_t m0 = (size_t)blockIdx.y * 128;
  const size_t n0 = (size_t)blockIdx.x * 128;
  const unsigned short* gA = A + m0 * K;
  const unsigned short* gB = Bt + n0 * K;
  const int srow = lane >> 2;        // 0..15: row within 16-row chunk
  const int scol = (lane & 3) * 8;   // element col within 32-wide row

  f32x4 acc[4][4] = {};
  const int nk = K >> 5;

  auto stage = [&](int buf, int kt) {
#pragma unroll
    for (int i = 0; i < 2; ++i) {
      const int r = w * 32 + i * 16;
      gload_lds16(gA + (size_t)(r + srow) * K + kt * 32 + scol, &sA[buf][r * 32]);
      gload_lds16(gB + (size_t)(r + srow) * K + kt * 32 + scol, &sB[buf][r * 32]);
    }
  };

  stage(0, 0);
  __syncthreads();
  int cur = 0;
  for (int kt = 0; kt < nk; ++kt) {
    if (kt + 1 < nk) stage(cur ^ 1, kt + 1);
    bf16x8 af[4], bfr[4];
#pragma unroll
    for (int i = 0; i < 4; ++i) {
      af[i]  = *(const bf16x8*)&sA[cur][(wm * 64 + i * 16 + lr) * 32 + lg * 8];
      bfr[i] = *(const bf16x8*)&sB[cur][(wn * 64 + i * 16 + lr) * 32 + lg * 8];
    }
#pragma unroll
    for (int i = 0; i < 4; ++i)
#pragma unroll
      for (int j = 0; j < 4; ++j) acc[i][j] = mfma16(af[i], bfr[j], acc[i][j]);
    __syncthreads();   // drains vmcnt (next-tile staging) + closes read phase
    cur ^= 1;
  }

#pragma unroll
  for (int i = 0; i < 4; ++i) {
#pragma unroll
    for (int j = 0; j < 4; ++j) {
#pragma unroll
      for (int r = 0; r < 4; ++r) {
        const int m = (int)m0 + wm * 64 + i * 16 + lg * 4 + r;
        const int n = (int)n0 + wn * 64 + j * 16 + lr;
        float v = acc[i][j][r] + bias[n];
        if constexpr (MODE == MODE_QKV) {
          const int b = m >> 10, nq = m & 1023;
          if (n < 768) {
            const int h = n >> 6, dh = n & 63;
            o0[(((size_t)(b * NH + h)) * SEQ + nq) * DHD + dh] = f2bf(v);
          } else if (n < 1536) {
            const int n2 = n - 768, h = n2 >> 6, dh = n2 & 63;
            o1[(((size_t)(b * NH + h)) * SEQ + nq) * DHD + dh] = f2bf(v);
          } else {
            const int n2 = n - 1536, h = n2 >> 6, dh = n2 & 63;
            o2[(((size_t)(b * NH + h)) * DHD + dh) * SEQ + nq] = f2bf(v);  // V^T
          }
        } else if constexpr (MODE == MODE_PROJ) {
          const size_t off = (size_t)m * D_MODEL + n;
          outF[off] = v + resid[off];
        } else if constexpr (MODE == MODE_FFN1) {
          const float g3 = v * v * v;
          const float gl = 0.5f * v * (1.0f + tanhf(0.7978845608028654f * (v + 0.044715f * g3)));
          o0[(size_t)m * DFF + n] = f2bf(gl);
        } else {  // FFN2: in-place residual on outF (x2 lives there)
          const size_t off = (size_t)m * D_MODEL + n;
          outF[off] = v + resid[off];
        }
      }
    }
  }
}

// ---------------- fused flash attention: wave = 16 queries of one (b,h) ------
__global__ __launch_bounds__(256)
void attn_kernel(const unsigned short* __restrict__ q, const unsigned short* __restrict__ k,
                 const unsigned short* __restrict__ vt, const float* __restrict__ rb,
                 unsigned short* __restrict__ ctx) {
  __shared__ alignas(16) unsigned short pbuf[4][16 * 32];
  const int w = threadIdx.x >> 6, lane = threadIdx.x & 63;
  const int lr = lane & 15, lg = lane >> 4;
  const int bid = blockIdx.x;
  const int bh = bid >> 4, qb = bid & 15;
  const int b = bh / NH, h = bh % NH;
  const int q0 = qb * 64 + w * 16;
  const unsigned short* qp = q + ((size_t)bh * SEQ + q0) * DHD;
  const unsigned short* kp = k + (size_t)bh * SEQ * DHD;
  const unsigned short* vp = vt + (size_t)bh * DHD * SEQ;
  const float* bp = rb + ((size_t)h * SEQ + q0) * SEQ;

  bf16x8 aQ[2];
  aQ[0] = *(const bf16x8*)(qp + lr * DHD + lg * 8);
  aQ[1] = *(const bf16x8*)(qp + lr * DHD + 32 + lg * 8);

  f32x4 o[4] = {};
  float mrun[4], lrun[4];
#pragma unroll
  for (int r = 0; r < 4; ++r) { mrun[r] = -INFINITY; lrun[r] = 0.f; }
  const float scale = 0.125f;  // 1/sqrt(64)

  for (int kb = 0; kb < SEQ / 32; ++kb) {
    const unsigned short* kt0 = kp + (size_t)(kb * 32) * DHD;
    f32x4 s0 = {}, s1 = {};
    {
      bf16x8 b00 = *(const bf16x8*)(kt0 + lr * DHD + lg * 8);
      bf16x8 b01 = *(const bf16x8*)(kt0 + lr * DHD + 32 + lg * 8);
      s0 = mfma16(aQ[0], b00, s0);
      s0 = mfma16(aQ[1], b01, s0);
      bf16x8 b10 = *(const bf16x8*)(kt0 + (16 + lr) * DHD + lg * 8);
      bf16x8 b11 = *(const bf16x8*)(kt0 + (16 + lr) * DHD + 32 + lg * 8);
      s1 = mfma16(aQ[0], b10, s1);
      s1 = mfma16(aQ[1], b11, s1);
    }
    float p0[4], p1[4], t[4];
#pragma unroll
    for (int r = 0; r < 4; ++r) {
      const float* brow = bp + (size_t)(lg * 4 + r) * SEQ + kb * 32;
      p0[r] = s0[r] * scale + brow[lr];
      p1[r] = s1[r] * scale + brow[16 + lr];
      t[r] = fmaxf(p0[r], p1[r]);
    }
#pragma unroll
    for (int r = 0; r < 4; ++r)
#pragma unroll
      for (int off = 8; off; off >>= 1) t[r] = fmaxf(t[r], __shfl_xor(t[r], off));
    float al[4], rsum[4];
#pragma unroll
    for (int r = 0; r < 4; ++r) {
      const float mn = fmaxf(mrun[r], t[r]);
      al[r] = __expf(mrun[r] - mn);
      mrun[r] = mn;
      p0[r] = __expf(p0[r] - mn);
      p1[r] = __expf(p1[r] - mn);
      rsum[r] = p0[r] + p1[r];
    }
#pragma unroll
    for (int r = 0; r < 4; ++r)
#pragma unroll
      for (int off = 8; off; off >>= 1) rsum[r] += __shfl_xor(rsum[r], off);
#pragma unroll
    for (int r = 0; r < 4; ++r) lrun[r] = lrun[r] * al[r] + rsum[r];
#pragma unroll
    for (int db = 0; db < 4; ++db)
#pragma unroll
      for (int r = 0; r < 4; ++r) o[db][r] *= al[r];
    unsigned short* pb = pbuf[w];
#pragma unroll
    for (int r = 0; r < 4; ++r) {
      pb[(lg * 4 + r) * 32 + lr] = f2bf(p0[r]);
      pb[(lg * 4 + r) * 32 + 16 + lr] = f2bf(p1[r]);
    }
    __syncthreads();  // write->read ordering for pbuf (wave-local, cheap insurance)
    bf16x8 aP = *(const bf16x8*)(pb + lr * 32 + lg * 8);
    const unsigned short* vb = vp + kb * 32;
#pragma unroll
    for (int db = 0; db < 4; ++db) {
      bf16x8 bV = *(const bf16x8*)(vb + (size_t)(db * 16 + lr) * SEQ + lg * 8);
      o[db] = mfma16(aP, bV, o[db]);
    }
  }
#pragma unroll
  for (int r = 0; r < 4; ++r) {
    const float inv = 1.0f / lrun[r];
    const size_t row = (size_t)b * SEQ + q0 + lg * 4 + r;
#pragma unroll
    for (int db = 0; db < 4; ++db)
      ctx[row * D_MODEL + h * DHD + db * 16 + lr] = f2bf(o[db][r] * inv);
  }
}

// ----------------------------------------------------------------------------
extern "C" void kernel_launch(void* const* d_in, const int* in_sizes, int n_in,
                              void* d_out, int out_size, void* d_ws, size_t ws_size,
                              hipStream_t stream) {
  (void)in_sizes; (void)n_in; (void)out_size; (void)ws_size;
  const float* x     = (const float*)d_in[0];
  const float* ln1_g = (const float*)d_in[1];
  const float* ln1_b = (const float*)d_in[2];
  const float* wqkv  = (const float*)d_in[3];
  const float* bqkv  = (const float*)d_in[4];
  const float* wo    = (const float*)d_in[5];
  const float* bo    = (const float*)d_in[6];
  const float* rel   = (const float*)d_in[7];
  const float* ln2_g = (const float*)d_in[8];
  const float* ln2_b = (const float*)d_in[9];
  const float* w1    = (const float*)d_in[10];
  const float* b1    = (const float*)d_in[11];
  const float* w2    = (const float*)d_in[12];
  const float* b2    = (const float*)d_in[13];
  float* out = (float*)d_out;

  char* p = (char*)d_ws;
  auto take = [&](size_t bytes) {
    void* r = (void*)p;
    p += (bytes + 255) & ~(size_t)255;
    return r;
  };
  unsigned short* hbuf  = (unsigned short*)take((size_t)NTOK * D_MODEL * 2);
  unsigned short* wqkvT = (unsigned short*)take((size_t)2304 * 768 * 2);
  unsigned short* woT   = (unsigned short*)take((size_t)768 * 768 * 2);
  unsigned short* w1T   = (unsigned short*)take((size_t)3072 * 768 * 2);
  unsigned short* w2T   = (unsigned short*)take((size_t)768 * 3072 * 2);
  unsigned short* qbuf  = (unsigned short*)take((size_t)8 * NH * SEQ * DHD * 2);
  unsigned short* kbuf  = (unsigned short*)take((size_t)8 * NH * SEQ * DHD * 2);
  unsigned short* vtbuf = (unsigned short*)take((size_t)8 * NH * SEQ * DHD * 2);
  unsigned short* ctxb  = (unsigned short*)take((size_t)NTOK * D_MODEL * 2);
  unsigned short* h1buf = (unsigned short*)take((size_t)NTOK * DFF * 2);
  // x2 (post-attention residual stream) lives in d_out (fp32).

  // weight prep (independent of activations)
  wtrans_kernel<<<dim3(2304 / 32, 768 / 32), 256, 0, stream>>>(wqkv, wqkvT, 768, 2304);
  wtrans_kernel<<<dim3(768 / 32, 768 / 32), 256, 0, stream>>>(wo, woT, 768, 768);
  wtrans_kernel<<<dim3(3072 / 32, 768 / 32), 256, 0, stream>>>(w1, w1T, 768, 3072);
  wtrans_kernel<<<dim3(768 / 32, 3072 / 32), 256, 0, stream>>>(w2, w2T, 3072, 768);

  // LN1: x -> h (bf16)
  ln_kernel<<<NTOK / 4, 256, 0, stream>>>(x, ln1_g, ln1_b, hbuf);
  // QKV: h @ wqkv + bqkv -> q,k,Vt (bf16, attention layouts)
  gemm_bt<MODE_QKV><<<dim3(2304 / 128, NTOK / 128), 256, 0, stream>>>(
      hbuf, wqkvT, 768, bqkv, nullptr, nullptr, qbuf, kbuf, vtbuf);
  // attention -> ctx (bf16, [tok][D])
  attn_kernel<<<8 * NH * (SEQ / 64), 256, 0, stream>>>(qbuf, kbuf, vtbuf, rel, ctxb);
  // proj: ctx @ wo + bo + x -> x2 (fp32, in d_out)
  gemm_bt<MODE_PROJ><<<dim3(768 / 128, NTOK / 128), 256, 0, stream>>>(
      ctxb, woT, 768, bo, x, out, nullptr, nullptr, nullptr);
  // LN2: x2 -> h2 (bf16, reuse hbuf)
  ln_kernel<<<NTOK / 4, 256, 0, stream>>>(out, ln2_g, ln2_b, hbuf);
  // FFN1: h2 @ w1 + b1, gelu -> h1 (bf16)
  gemm_bt<MODE_FFN1><<<dim3(DFF / 128, NTOK / 128), 256, 0, stream>>>(
      hbuf, w1T, 768, b1, nullptr, nullptr, h1buf, nullptr, nullptr);
  // FFN2: h1 @ w2 + b2 + x2 -> out (fp32, in place on d_out)
  gemm_bt<MODE_FFN2><<<dim3(768 / 128, NTOK / 128), 256, 0, stream>>>(
      h1buf, w2T, 3072, b2, out, out, nullptr, nullptr, nullptr);
}

// Round 2
// 469.026 us; speedup vs baseline: 1.0128x; 1.0128x over previous
//
#include <hip/hip_runtime.h>
#include <hip/hip_bf16.h>
#include <math.h>

#define D_MODEL 768
#define NTOK    8192   // B*N
#define SEQ     1024
#define NH      12
#define DHD     64
#define DFF     3072

typedef __attribute__((ext_vector_type(8))) __bf16 bf16x8;
typedef __attribute__((ext_vector_type(4))) float  f32x4;
typedef __attribute__((ext_vector_type(4))) unsigned short us4;

typedef const __attribute__((address_space(1))) void g_void;
typedef __attribute__((address_space(3))) void lds_void;

__device__ __forceinline__ unsigned short f2bf(float f) {
  unsigned u = __float_as_uint(f);
  u += 0x7fffu + ((u >> 16) & 1u);   // RNE to bf16
  return (unsigned short)(u >> 16);
}

__device__ __forceinline__ f32x4 mfma16(bf16x8 a, bf16x8 b, f32x4 c) {
  return __builtin_amdgcn_mfma_f32_16x16x32_bf16(a, b, c, 0, 0, 0);
}

// async global->LDS, 16B per lane; LDS dest = uniform base + lane*16
__device__ __forceinline__ void gload_lds16(const unsigned short* g, unsigned short* l) {
  __builtin_amdgcn_global_load_lds((g_void*)g, (lds_void*)l, 16, 0, 0);
}

// ---------------- LayerNorm: one wave per row of 768, fp32 in -> bf16 out ----
__global__ __launch_bounds__(256)
void ln_kernel(const float* __restrict__ x, const float* __restrict__ gam,
               const float* __restrict__ bet, unsigned short* __restrict__ out) {
  const int w = threadIdx.x >> 6, lane = threadIdx.x & 63;
  const size_t row = (size_t)blockIdx.x * 4 + w;
  const float* xr = x + row * D_MODEL;
  f32x4 v[3];
#pragma unroll
  for (int c = 0; c < 3; ++c) v[c] = *(const f32x4*)(xr + c * 256 + lane * 4);
  float s = 0.f;
#pragma unroll
  for (int c = 0; c < 3; ++c)
#pragma unroll
    for (int j = 0; j < 4; ++j) s += v[c][j];
#pragma unroll
  for (int o = 32; o; o >>= 1) s += __shfl_xor(s, o);
  const float mu = s * (1.0f / D_MODEL);
  float vs = 0.f;
#pragma unroll
  for (int c = 0; c < 3; ++c)
#pragma unroll
    for (int j = 0; j < 4; ++j) { float d = v[c][j] - mu; vs += d * d; }
#pragma unroll
  for (int o = 32; o; o >>= 1) vs += __shfl_xor(vs, o);
  const float rs = rsqrtf(vs * (1.0f / D_MODEL) + 1e-5f);
  unsigned short* orow = out + row * D_MODEL;
#pragma unroll
  for (int c = 0; c < 3; ++c) {
    us4 o4;
#pragma unroll
    for (int j = 0; j < 4; ++j) {
      int idx = c * 256 + lane * 4 + j;
      o4[j] = f2bf((v[c][j] - mu) * rs * gam[idx] + bet[idx]);
    }
    *(us4*)(orow + c * 256 + lane * 4) = o4;
  }
}

// ------------- weight transpose + cast: W[K][Nc] f32 -> Wt[Nc][K] bf16 -------
__global__ __launch_bounds__(256)
void wtrans_kernel(const float* __restrict__ W, unsigned short* __restrict__ Wt,
                   int K, int Nc) {
  __shared__ float t[32][33];
  const int tx = threadIdx.x & 31, ty = threadIdx.x >> 5;  // 32x8
  const int nb = blockIdx.x * 32, kb = blockIdx.y * 32;
#pragma unroll
  for (int i = 0; i < 4; ++i)
    t[ty + 8 * i][tx] = W[(size_t)(kb + ty + 8 * i) * Nc + nb + tx];
  __syncthreads();
#pragma unroll
  for (int i = 0; i < 4; ++i)
    Wt[(size_t)(nb + ty + 8 * i) * K + kb + tx] = f2bf(t[tx][ty + 8 * i]);
}

// ---------------- GEMM: C[M][N] = A[M][K] @ Bt[N][K]^T, bf16 in, fused epilogue
#define MODE_QKV  0
#define MODE_PROJ 1
#define MODE_FFN1 2
#define MODE_FFN2 3

template <int MODE>
__global__ __launch_bounds__(256)
void gemm_bt(const unsigned short* __restrict__ A, const unsigned short* __restrict__ Bt,
             int K, const float* __restrict__ bias, const float* __restrict__ resid,
             float* __restrict__ outF, unsigned short* __restrict__ o0,
             unsigned short* __restrict__ o1, unsigned short* __restrict__ o2) {
  __shared__ alignas(16) unsigned short sA[2][128 * 32];
  __shared__ alignas(16) unsigned short sB[2][128 * 32];
  const int tid = threadIdx.x;
  const int w = tid >> 6, lane = tid & 63;
  const int lr = lane & 15, lg = lane >> 4;
  const int wm = w >> 1, wn = w & 1;
  const size_t m0 = (size_t)blockIdx.y * 128;
  const size_t n0 = (size_t)blockIdx.x * 128;
  const unsigned short* gA = A + m0 * K;
  const unsigned short* gB = Bt + n0 * K;
  const int srow = lane >> 2;        // 0..15: row within 16-row chunk
  const int scol = (lane & 3) * 8;   // element col within 32-wide row

  f32x4 acc[4][4] = {};
  const int nk = K >> 5;

  auto stage = [&](int buf, int kt) {
#pragma unroll
    for (int i = 0; i < 2; ++i) {
      const int r = w * 32 + i * 16;
      gload_lds16(gA + (size_t)(r + srow) * K + kt * 32 + scol, &sA[buf][r * 32]);
      gload_lds16(gB + (size_t)(r + srow) * K + kt * 32 + scol, &sB[buf][r * 32]);
    }
  };

  stage(0, 0);
  __syncthreads();
  int cur = 0;
  for (int kt = 0; kt < nk; ++kt) {
    if (kt + 1 < nk) stage(cur ^ 1, kt + 1);
    bf16x8 af[4], bfr[4];
#pragma unroll
    for (int i = 0; i < 4; ++i) {
      af[i]  = *(const bf16x8*)&sA[cur][(wm * 64 + i * 16 + lr) * 32 + lg * 8];
      bfr[i] = *(const bf16x8*)&sB[cur][(wn * 64 + i * 16 + lr) * 32 + lg * 8];
    }
#pragma unroll
    for (int i = 0; i < 4; ++i)
#pragma unroll
      for (int j = 0; j < 4; ++j) acc[i][j] = mfma16(af[i], bfr[j], acc[i][j]);
    __syncthreads();   // drains vmcnt (next-tile staging) + closes read phase
    cur ^= 1;
  }

#pragma unroll
  for (int i = 0; i < 4; ++i) {
#pragma unroll
    for (int j = 0; j < 4; ++j) {
#pragma unroll
      for (int r = 0; r < 4; ++r) {
        const int m = (int)m0 + wm * 64 + i * 16 + lg * 4 + r;
        const int n = (int)n0 + wn * 64 + j * 16 + lr;
        float v = acc[i][j][r] + bias[n];
        if constexpr (MODE == MODE_QKV) {
          const int b = m >> 10, nq = m & 1023;
          if (n < 768) {
            const int h = n >> 6, dh = n & 63;
            o0[(((size_t)(b * NH + h)) * SEQ + nq) * DHD + dh] = f2bf(v);
          } else if (n < 1536) {
            const int n2 = n - 768, h = n2 >> 6, dh = n2 & 63;
            o1[(((size_t)(b * NH + h)) * SEQ + nq) * DHD + dh] = f2bf(v);
          } else {
            const int n2 = n - 1536, h = n2 >> 6, dh = n2 & 63;
            o2[(((size_t)(b * NH + h)) * DHD + dh) * SEQ + nq] = f2bf(v);  // V^T
          }
        } else if constexpr (MODE == MODE_PROJ) {
          const size_t off = (size_t)m * D_MODEL + n;
          outF[off] = v + resid[off];
        } else if constexpr (MODE == MODE_FFN1) {
          const float g3 = v * v * v;
          const float gl = 0.5f * v * (1.0f + tanhf(0.7978845608028654f * (v + 0.044715f * g3)));
          o0[(size_t)m * DFF + n] = f2bf(gl);
        } else {  // FFN2: in-place residual on outF (x2 lives there)
          const size_t off = (size_t)m * D_MODEL + n;
          outF[off] = v + resid[off];
        }
      }
    }
  }
}

// ------- fused flash attention, swapped-operand (S^T = K·Q^T) ---------------
// wave = 16 queries of one (b,h); lane: lr = q, (lg,reg) = k. No barriers.
__global__ __launch_bounds__(256)
void attn_kernel(const unsigned short* __restrict__ q, const unsigned short* __restrict__ k,
                 const unsigned short* __restrict__ vt, const float* __restrict__ rb,
                 unsigned short* __restrict__ ctx) {
  constexpr int PSTR = 40;  // shorts; 80B row stride: 16B-aligned b128 reads, even bank spread
  __shared__ alignas(16) unsigned short pbuf[4][16 * PSTR];
  const int w = threadIdx.x >> 6, lane = threadIdx.x & 63;
  const int lr = lane & 15, lg = lane >> 4;
  const int bid = blockIdx.x;
  const int bh = bid >> 4, qb = bid & 15;
  const int b = bh / NH, h = bh % NH;
  const int q0 = qb * 64 + w * 16;
  const unsigned short* qp = q + ((size_t)bh * SEQ + q0) * DHD;
  const unsigned short* kp = k + (size_t)bh * SEQ * DHD;
  const unsigned short* vp = vt + (size_t)bh * DHD * SEQ;
  const float* bp = rb + ((size_t)h * SEQ + q0 + lr) * SEQ;  // per-lane bias row (q = lr)

  bf16x8 aQ[2];
  aQ[0] = *(const bf16x8*)(qp + lr * DHD + lg * 8);
  aQ[1] = *(const bf16x8*)(qp + lr * DHD + 32 + lg * 8);

  f32x4 o[4] = {};               // O^T: lane q = lr, rows d = dt*16 + lg*4 + r
  float mrun = -INFINITY, lrun = 0.f;
  const float scale = 0.125f;    // 1/sqrt(64)
  unsigned short* pb = pbuf[w];

  for (int kb = 0; kb < SEQ / 32; ++kb) {
    const unsigned short* kt0 = kp + (size_t)(kb * 32) * DHD;
    const unsigned short* vb = vp + kb * 32;
    // issue all global loads for this iteration up front (ILP)
    bf16x8 kf[4], vf[4];
    kf[0] = *(const bf16x8*)(kt0 + lr * DHD + lg * 8);
    kf[1] = *(const bf16x8*)(kt0 + lr * DHD + 32 + lg * 8);
    kf[2] = *(const bf16x8*)(kt0 + (16 + lr) * DHD + lg * 8);
    kf[3] = *(const bf16x8*)(kt0 + (16 + lr) * DHD + 32 + lg * 8);
    f32x4 bias0 = *(const f32x4*)(bp + kb * 32 + lg * 4);
    f32x4 bias1 = *(const f32x4*)(bp + kb * 32 + 16 + lg * 4);
#pragma unroll
    for (int dt = 0; dt < 4; ++dt)
      vf[dt] = *(const bf16x8*)(vb + (size_t)(dt * 16 + lr) * SEQ + lg * 8);

    // S^T tiles: s0 covers k 0..15 of this block, s1 covers k 16..31
    f32x4 s0 = {}, s1 = {};
    __builtin_amdgcn_s_setprio(1);
    s0 = mfma16(kf[0], aQ[0], s0);
    s0 = mfma16(kf[1], aQ[1], s0);
    s1 = mfma16(kf[2], aQ[0], s1);
    s1 = mfma16(kf[3], aQ[1], s1);
    __builtin_amdgcn_s_setprio(0);

    float p0[4], p1[4];
#pragma unroll
    for (int r = 0; r < 4; ++r) {
      p0[r] = fmaf(s0[r], scale, bias0[r]);
      p1[r] = fmaf(s1[r], scale, bias1[r]);
    }
    // row-max over k: 7 in-register fmax + 2 cross-group shuffles
    float pm = fmaxf(fmaxf(fmaxf(p0[0], p0[1]), fmaxf(p0[2], p0[3])),
                     fmaxf(fmaxf(p1[0], p1[1]), fmaxf(p1[2], p1[3])));
    pm = fmaxf(pm, __shfl_xor(pm, 16));
    pm = fmaxf(pm, __shfl_xor(pm, 32));
    const float mn = fmaxf(mrun, pm);
    const float al = __expf(mrun - mn);
    mrun = mn;
    float rs = 0.f;
#pragma unroll
    for (int r = 0; r < 4; ++r) {
      p0[r] = __expf(p0[r] - mn);
      p1[r] = __expf(p1[r] - mn);
      rs += p0[r] + p1[r];
    }
    rs += __shfl_xor(rs, 16);
    rs += __shfl_xor(rs, 32);
    lrun = lrun * al + rs;
#pragma unroll
    for (int dt = 0; dt < 4; ++dt)
#pragma unroll
      for (int r = 0; r < 4; ++r) o[dt][r] *= al;
    // P round-trip through wave-private LDS: [16 q][32 k] (padded stride)
    us4 w0, w1;
#pragma unroll
    for (int r = 0; r < 4; ++r) { w0[r] = f2bf(p0[r]); w1[r] = f2bf(p1[r]); }
    *(us4*)(pb + lr * PSTR + lg * 4) = w0;
    *(us4*)(pb + lr * PSTR + 16 + lg * 4) = w1;
    bf16x8 pfrag = *(const bf16x8*)(pb + lr * PSTR + lg * 8);  // P[q=lr][k=lg*8..+7]
    __builtin_amdgcn_s_setprio(1);
#pragma unroll
    for (int dt = 0; dt < 4; ++dt) o[dt] = mfma16(vf[dt], pfrag, o[dt]);
    __builtin_amdgcn_s_setprio(0);
  }
  const float inv = 1.0f / lrun;
  unsigned short* crow = ctx + ((size_t)b * SEQ + q0 + lr) * D_MODEL + h * DHD;
#pragma unroll
  for (int dt = 0; dt < 4; ++dt) {
    us4 o4;
#pragma unroll
    for (int r = 0; r < 4; ++r) o4[r] = f2bf(o[dt][r] * inv);
    *(us4*)(crow + dt * 16 + lg * 4) = o4;
  }
}

// ----------------------------------------------------------------------------
extern "C" void kernel_launch(void* const* d_in, const int* in_sizes, int n_in,
                              void* d_out, int out_size, void* d_ws, size_t ws_size,
                              hipStream_t stream) {
  (void)in_sizes; (void)n_in; (void)out_size; (void)ws_size;
  const float* x     = (const float*)d_in[0];
  const float* ln1_g = (const float*)d_in[1];
  const float* ln1_b = (const float*)d_in[2];
  const float* wqkv  = (const float*)d_in[3];
  const float* bqkv  = (const float*)d_in[4];
  const float* wo    = (const float*)d_in[5];
  const float* bo    = (const float*)d_in[6];
  const float* rel   = (const float*)d_in[7];
  const float* ln2_g = (const float*)d_in[8];
  const float* ln2_b = (const float*)d_in[9];
  const float* w1    = (const float*)d_in[10];
  const float* b1    = (const float*)d_in[11];
  const float* w2    = (const float*)d_in[12];
  const float* b2    = (const float*)d_in[13];
  float* out = (float*)d_out;

  char* p = (char*)d_ws;
  auto take = [&](size_t bytes) {
    void* r = (void*)p;
    p += (bytes + 255) & ~(size_t)255;
    return r;
  };
  unsigned short* hbuf  = (unsigned short*)take((size_t)NTOK * D_MODEL * 2);
  unsigned short* wqkvT = (unsigned short*)take((size_t)2304 * 768 * 2);
  unsigned short* woT   = (unsigned short*)take((size_t)768 * 768 * 2);
  unsigned short* w1T   = (unsigned short*)take((size_t)3072 * 768 * 2);
  unsigned short* w2T   = (unsigned short*)take((size_t)768 * 3072 * 2);
  unsigned short* qbuf  = (unsigned short*)take((size_t)8 * NH * SEQ * DHD * 2);
  unsigned short* kbuf  = (unsigned short*)take((size_t)8 * NH * SEQ * DHD * 2);
  unsigned short* vtbuf = (unsigned short*)take((size_t)8 * NH * SEQ * DHD * 2);
  unsigned short* ctxb  = (unsigned short*)take((size_t)NTOK * D_MODEL * 2);
  unsigned short* h1buf = (unsigned short*)take((size_t)NTOK * DFF * 2);
  // x2 (post-attention residual stream) lives in d_out (fp32).

  // weight prep (independent of activations)
  wtrans_kernel<<<dim3(2304 / 32, 768 / 32), 256, 0, stream>>>(wqkv, wqkvT, 768, 2304);
  wtrans_kernel<<<dim3(768 / 32, 768 / 32), 256, 0, stream>>>(wo, woT, 768, 768);
  wtrans_kernel<<<dim3(3072 / 32, 768 / 32), 256, 0, stream>>>(w1, w1T, 768, 3072);
  wtrans_kernel<<<dim3(768 / 32, 3072 / 32), 256, 0, stream>>>(w2, w2T, 3072, 768);

  // LN1: x -> h (bf16)
  ln_kernel<<<NTOK / 4, 256, 0, stream>>>(x, ln1_g, ln1_b, hbuf);
  // QKV: h @ wqkv + bqkv -> q,k,Vt (bf16, attention layouts)
  gemm_bt<MODE_QKV><<<dim3(2304 / 128, NTOK / 128), 256, 0, stream>>>(
      hbuf, wqkvT, 768, bqkv, nullptr, nullptr, qbuf, kbuf, vtbuf);
  // attention -> ctx (bf16, [tok][D])
  attn_kernel<<<8 * NH * (SEQ / 64), 256, 0, stream>>>(qbuf, kbuf, vtbuf, rel, ctxb);
  // proj: ctx @ wo + bo + x -> x2 (fp32, in d_out)
  gemm_bt<MODE_PROJ><<<dim3(768 / 128, NTOK / 128), 256, 0, stream>>>(
      ctxb, woT, 768, bo, x, out, nullptr, nullptr, nullptr);
  // LN2: x2 -> h2 (bf16, reuse hbuf)
  ln_kernel<<<NTOK / 4, 256, 0, stream>>>(out, ln2_g, ln2_b, hbuf);
  // FFN1: h2 @ w1 + b1, gelu -> h1 (bf16)
  gemm_bt<MODE_FFN1><<<dim3(DFF / 128, NTOK / 128), 256, 0, stream>>>(
      hbuf, w1T, 768, b1, nullptr, nullptr, h1buf, nullptr, nullptr);
  // FFN2: h1 @ w2 + b2 + x2 -> out (fp32, in place on d_out)
  gemm_bt<MODE_FFN2><<<dim3(768 / 128, NTOK / 128), 256, 0, stream>>>(
      h1buf, w2T, 3072, b2, out, out, nullptr, nullptr, nullptr);
}

// Round 3
// 467.561 us; speedup vs baseline: 1.0160x; 1.0031x over previous
//
#include <hip/hip_runtime.h>
#include <hip/hip_bf16.h>
#include <math.h>

#define D_MODEL 768
#define NTOK    8192   // B*N
#define SEQ     1024
#define NH      12
#define DHD     64
#define DFF     3072

typedef __attribute__((ext_vector_type(8))) __bf16 bf16x8;
typedef __attribute__((ext_vector_type(4))) float  f32x4;
typedef __attribute__((ext_vector_type(4))) unsigned short us4;

typedef const __attribute__((address_space(1))) void g_void;
typedef __attribute__((address_space(3))) void lds_void;

__device__ __forceinline__ unsigned short f2bf(float f) {
  unsigned u = __float_as_uint(f);
  u += 0x7fffu + ((u >> 16) & 1u);   // RNE to bf16
  return (unsigned short)(u >> 16);
}

__device__ __forceinline__ f32x4 mfma16(bf16x8 a, bf16x8 b, f32x4 c) {
  return __builtin_amdgcn_mfma_f32_16x16x32_bf16(a, b, c, 0, 0, 0);
}

// async global->LDS, 16B per lane; LDS dest = uniform base + lane*16
__device__ __forceinline__ void gload_lds16(const unsigned short* g, unsigned short* l) {
  __builtin_amdgcn_global_load_lds((g_void*)g, (lds_void*)l, 16, 0, 0);
}

// ---------------- LayerNorm: one wave per row of 768, fp32 in -> bf16 out ----
__global__ __launch_bounds__(256)
void ln_kernel(const float* __restrict__ x, const float* __restrict__ gam,
               const float* __restrict__ bet, unsigned short* __restrict__ out) {
  const int w = threadIdx.x >> 6, lane = threadIdx.x & 63;
  const size_t row = (size_t)blockIdx.x * 4 + w;
  const float* xr = x + row * D_MODEL;
  f32x4 v[3];
#pragma unroll
  for (int c = 0; c < 3; ++c) v[c] = *(const f32x4*)(xr + c * 256 + lane * 4);
  float s = 0.f;
#pragma unroll
  for (int c = 0; c < 3; ++c)
#pragma unroll
    for (int j = 0; j < 4; ++j) s += v[c][j];
#pragma unroll
  for (int o = 32; o; o >>= 1) s += __shfl_xor(s, o);
  const float mu = s * (1.0f / D_MODEL);
  float vs = 0.f;
#pragma unroll
  for (int c = 0; c < 3; ++c)
#pragma unroll
    for (int j = 0; j < 4; ++j) { float d = v[c][j] - mu; vs += d * d; }
#pragma unroll
  for (int o = 32; o; o >>= 1) vs += __shfl_xor(vs, o);
  const float rs = rsqrtf(vs * (1.0f / D_MODEL) + 1e-5f);
  unsigned short* orow = out + row * D_MODEL;
#pragma unroll
  for (int c = 0; c < 3; ++c) {
    us4 o4;
#pragma unroll
    for (int j = 0; j < 4; ++j) {
      int idx = c * 256 + lane * 4 + j;
      o4[j] = f2bf((v[c][j] - mu) * rs * gam[idx] + bet[idx]);
    }
    *(us4*)(orow + c * 256 + lane * 4) = o4;
  }
}

// ------------- weight transpose + cast: W[K][Nc] f32 -> Wt[Nc][K] bf16 -------
__global__ __launch_bounds__(256)
void wtrans_kernel(const float* __restrict__ W, unsigned short* __restrict__ Wt,
                   int K, int Nc) {
  __shared__ float t[32][33];
  const int tx = threadIdx.x & 31, ty = threadIdx.x >> 5;  // 32x8
  const int nb = blockIdx.x * 32, kb = blockIdx.y * 32;
#pragma unroll
  for (int i = 0; i < 4; ++i)
    t[ty + 8 * i][tx] = W[(size_t)(kb + ty + 8 * i) * Nc + nb + tx];
  __syncthreads();
#pragma unroll
  for (int i = 0; i < 4; ++i)
    Wt[(size_t)(nb + ty + 8 * i) * K + kb + tx] = f2bf(t[tx][ty + 8 * i]);
}

// ---------------- GEMM: C[M][N] = A[M][K] @ Bt[N][K]^T, bf16 in, fused epilogue
#define MODE_QKV  0
#define MODE_PROJ 1
#define MODE_FFN1 2
#define MODE_FFN2 3

template <int MODE>
__global__ __launch_bounds__(256)
void gemm_bt(const unsigned short* __restrict__ A, const unsigned short* __restrict__ Bt,
             int K, const float* __restrict__ bias, const float* __restrict__ resid,
             float* __restrict__ outF, unsigned short* __restrict__ o0,
             unsigned short* __restrict__ o1, unsigned short* __restrict__ o2) {
  __shared__ alignas(16) unsigned short sA[2][128 * 32];
  __shared__ alignas(16) unsigned short sB[2][128 * 32];
  const int tid = threadIdx.x;
  const int w = tid >> 6, lane = tid & 63;
  const int lr = lane & 15, lg = lane >> 4;
  const int wm = w >> 1, wn = w & 1;
  const size_t m0 = (size_t)blockIdx.y * 128;
  const size_t n0 = (size_t)blockIdx.x * 128;
  const unsigned short* gA = A + m0 * K;
  const unsigned short* gB = Bt + n0 * K;
  const int srow = lane >> 2;        // 0..15: row within 16-row chunk
  const int scol = (lane & 3) * 8;   // element col within 32-wide row

  f32x4 acc[4][4] = {};
  const int nk = K >> 5;

  auto stage = [&](int buf, int kt) {
#pragma unroll
    for (int i = 0; i < 2; ++i) {
      const int r = w * 32 + i * 16;
      gload_lds16(gA + (size_t)(r + srow) * K + kt * 32 + scol, &sA[buf][r * 32]);
      gload_lds16(gB + (size_t)(r + srow) * K + kt * 32 + scol, &sB[buf][r * 32]);
    }
  };

  stage(0, 0);
  __syncthreads();
  int cur = 0;
  for (int kt = 0; kt < nk; ++kt) {
    if (kt + 1 < nk) stage(cur ^ 1, kt + 1);
    bf16x8 af[4], bfr[4];
#pragma unroll
    for (int i = 0; i < 4; ++i) {
      af[i]  = *(const bf16x8*)&sA[cur][(wm * 64 + i * 16 + lr) * 32 + lg * 8];
      bfr[i] = *(const bf16x8*)&sB[cur][(wn * 64 + i * 16 + lr) * 32 + lg * 8];
    }
#pragma unroll
    for (int i = 0; i < 4; ++i)
#pragma unroll
      for (int j = 0; j < 4; ++j) acc[i][j] = mfma16(af[i], bfr[j], acc[i][j]);
    __syncthreads();   // drains vmcnt (next-tile staging) + closes read phase
    cur ^= 1;
  }

#pragma unroll
  for (int i = 0; i < 4; ++i) {
#pragma unroll
    for (int j = 0; j < 4; ++j) {
#pragma unroll
      for (int r = 0; r < 4; ++r) {
        const int m = (int)m0 + wm * 64 + i * 16 + lg * 4 + r;
        const int n = (int)n0 + wn * 64 + j * 16 + lr;
        float v = acc[i][j][r] + bias[n];
        if constexpr (MODE == MODE_QKV) {
          const int b = m >> 10, nq = m & 1023;
          if (n < 768) {
            const int h = n >> 6, dh = n & 63;
            o0[(((size_t)(b * NH + h)) * SEQ + nq) * DHD + dh] = f2bf(v);
          } else if (n < 1536) {
            const int n2 = n - 768, h = n2 >> 6, dh = n2 & 63;
            o1[(((size_t)(b * NH + h)) * SEQ + nq) * DHD + dh] = f2bf(v);
          } else {
            const int n2 = n - 1536, h = n2 >> 6, dh = n2 & 63;
            o2[(((size_t)(b * NH + h)) * DHD + dh) * SEQ + nq] = f2bf(v);  // V^T
          }
        } else if constexpr (MODE == MODE_PROJ) {
          const size_t off = (size_t)m * D_MODEL + n;
          outF[off] = v + resid[off];
        } else if constexpr (MODE == MODE_FFN1) {
          const float g3 = v * v * v;
          const float gl = 0.5f * v * (1.0f + tanhf(0.7978845608028654f * (v + 0.044715f * g3)));
          o0[(size_t)m * DFF + n] = f2bf(gl);
        } else {  // FFN2: in-place residual on outF (x2 lives there)
          const size_t off = (size_t)m * D_MODEL + n;
          outF[off] = v + resid[off];
        }
      }
    }
  }
}

// ------- fused flash attention, swapped-operand (S^T = K·Q^T) ---------------
// wave = 16 queries of one (b,h); lane: lr = q, (lg,reg) = k.
// KVBLK=64, register-dbuf'd K+bias prefetch, defer-max, per-lane lrun partial.
__global__ __launch_bounds__(256)
void attn_kernel(const unsigned short* __restrict__ q, const unsigned short* __restrict__ k,
                 const unsigned short* __restrict__ vt, const float* __restrict__ rb,
                 unsigned short* __restrict__ ctx) {
  constexpr int PSTR = 72;  // shorts; 144B row stride: 16B-aligned reads, 2-way banks max
  __shared__ alignas(16) unsigned short pbuf[4][16 * PSTR];
  const int w = threadIdx.x >> 6, lane = threadIdx.x & 63;
  const int lr = lane & 15, lg = lane >> 4;
  // XCD-chunked swizzle: 1536 blocks % 8 == 0 -> bijective. All 16 q-blocks of
  // one (b,h) land on one XCD -> K/V L2-resident.
  const int bid = (blockIdx.x & 7) * 192 + (blockIdx.x >> 3);
  const int bh = bid >> 4, qb = bid & 15;
  const int b = bh / NH, h = bh % NH;
  const int q0 = qb * 64 + w * 16;
  const unsigned short* qp = q + ((size_t)bh * SEQ + q0) * DHD;
  const unsigned short* kp = k + (size_t)bh * SEQ * DHD;
  const unsigned short* vp = vt + (size_t)bh * DHD * SEQ;
  const float* bp = rb + ((size_t)h * SEQ + q0 + lr) * SEQ;  // per-lane bias row (q = lr)

  bf16x8 aQ[2];
  aQ[0] = *(const bf16x8*)(qp + lr * DHD + lg * 8);
  aQ[1] = *(const bf16x8*)(qp + lr * DHD + 32 + lg * 8);

  f32x4 o[4] = {};               // O^T: lane q = lr, rows d = dt*16 + lg*4 + r
  float mrun = -INFINITY, lrun = 0.f;  // lrun: per-lane partial (reduced at end)
  const float scale = 0.125f;    // 1/sqrt(64)
  unsigned short* pb = pbuf[w];

  bf16x8 kfA[8], kfB[8];
  f32x4 bbA[4], bbB[4];

  auto loadKB = [&](bf16x8* kf, f32x4* bb, int kb64) {
    const unsigned short* kt0 = kp + (size_t)(kb64 * 64) * DHD;
#pragma unroll
    for (int st = 0; st < 4; ++st) {
      kf[2 * st]     = *(const bf16x8*)(kt0 + (st * 16 + lr) * DHD + lg * 8);
      kf[2 * st + 1] = *(const bf16x8*)(kt0 + (st * 16 + lr) * DHD + 32 + lg * 8);
      bb[st] = *(const f32x4*)(bp + kb64 * 64 + st * 16 + lg * 4);
    }
  };

  auto body = [&](const bf16x8* kf, const f32x4* bb, int kb64) {
    // V loads for THIS block issue first; latency hides under S-MFMA+softmax
    const unsigned short* vb = vp + kb64 * 64;
    bf16x8 vf[8];
#pragma unroll
    for (int dt = 0; dt < 4; ++dt) {
      vf[2 * dt]     = *(const bf16x8*)(vb + (size_t)(dt * 16 + lr) * SEQ + lg * 8);
      vf[2 * dt + 1] = *(const bf16x8*)(vb + (size_t)(dt * 16 + lr) * SEQ + 32 + lg * 8);
    }
    f32x4 s[4] = {};
    __builtin_amdgcn_s_setprio(1);
#pragma unroll
    for (int st = 0; st < 4; ++st) {
      s[st] = mfma16(kf[2 * st], aQ[0], s[st]);
      s[st] = mfma16(kf[2 * st + 1], aQ[1], s[st]);
    }
    __builtin_amdgcn_s_setprio(0);
    float p[16];
#pragma unroll
    for (int st = 0; st < 4; ++st)
#pragma unroll
      for (int r = 0; r < 4; ++r) p[st * 4 + r] = fmaf(s[st][r], scale, bb[st][r]);
    float pmax = p[0];
#pragma unroll
    for (int i = 1; i < 16; ++i) pmax = fmaxf(pmax, p[i]);
    // defer-max (T13): cross-lane reduce + rescale only when max grew > 8
    if (!__all(pmax - mrun <= 8.0f)) {
      float pm = pmax;
      pm = fmaxf(pm, __shfl_xor(pm, 16));
      pm = fmaxf(pm, __shfl_xor(pm, 32));
      const float mn = fmaxf(mrun, pm);
      const float al = __expf(mrun - mn);
      mrun = mn;
      lrun *= al;
#pragma unroll
      for (int dt = 0; dt < 4; ++dt)
#pragma unroll
        for (int r = 0; r < 4; ++r) o[dt][r] *= al;
    }
#pragma unroll
    for (int i = 0; i < 16; ++i) { p[i] = __expf(p[i] - mrun); lrun += p[i]; }
    // pack P to bf16 (cvt_pk) and round-trip through wave-private LDS
#pragma unroll
    for (int st = 0; st < 4; ++st) {
      uint2 w2;
      asm("v_cvt_pk_bf16_f32 %0, %1, %2" : "=v"(w2.x) : "v"(p[st * 4 + 0]), "v"(p[st * 4 + 1]));
      asm("v_cvt_pk_bf16_f32 %0, %1, %2" : "=v"(w2.y) : "v"(p[st * 4 + 2]), "v"(p[st * 4 + 3]));
      *(uint2*)(pb + lr * PSTR + st * 16 + lg * 4) = w2;
    }
    bf16x8 pf0 = *(const bf16x8*)(pb + lr * PSTR + lg * 8);        // keys 0..31
    bf16x8 pf1 = *(const bf16x8*)(pb + lr * PSTR + 32 + lg * 8);   // keys 32..63
    __builtin_amdgcn_s_setprio(1);
#pragma unroll
    for (int dt = 0; dt < 4; ++dt) {
      o[dt] = mfma16(vf[2 * dt], pf0, o[dt]);
      o[dt] = mfma16(vf[2 * dt + 1], pf1, o[dt]);
    }
    __builtin_amdgcn_s_setprio(0);
  };

  loadKB(kfA, bbA, 0);
  for (int kb = 0; kb < SEQ / 64; kb += 2) {
    if (kb + 1 < SEQ / 64) loadKB(kfB, bbB, kb + 1);
    body(kfA, bbA, kb);
    if (kb + 2 < SEQ / 64) loadKB(kfA, bbA, kb + 2);
    body(kfB, bbB, kb + 1);
  }

  lrun += __shfl_xor(lrun, 16);
  lrun += __shfl_xor(lrun, 32);
  const float inv = 1.0f / lrun;
  unsigned short* crow = ctx + ((size_t)b * SEQ + q0 + lr) * D_MODEL + h * DHD;
#pragma unroll
  for (int dt = 0; dt < 4; ++dt) {
    us4 o4;
#pragma unroll
    for (int r = 0; r < 4; ++r) o4[r] = f2bf(o[dt][r] * inv);
    *(us4*)(crow + dt * 16 + lg * 4) = o4;
  }
}

// ----------------------------------------------------------------------------
extern "C" void kernel_launch(void* const* d_in, const int* in_sizes, int n_in,
                              void* d_out, int out_size, void* d_ws, size_t ws_size,
                              hipStream_t stream) {
  (void)in_sizes; (void)n_in; (void)out_size; (void)ws_size;
  const float* x     = (const float*)d_in[0];
  const float* ln1_g = (const float*)d_in[1];
  const float* ln1_b = (const float*)d_in[2];
  const float* wqkv  = (const float*)d_in[3];
  const float* bqkv  = (const float*)d_in[4];
  const float* wo    = (const float*)d_in[5];
  const float* bo    = (const float*)d_in[6];
  const float* rel   = (const float*)d_in[7];
  const float* ln2_g = (const float*)d_in[8];
  const float* ln2_b = (const float*)d_in[9];
  const float* w1    = (const float*)d_in[10];
  const float* b1    = (const float*)d_in[11];
  const float* w2    = (const float*)d_in[12];
  const float* b2    = (const float*)d_in[13];
  float* out = (float*)d_out;

  char* p = (char*)d_ws;
  auto take = [&](size_t bytes) {
    void* r = (void*)p;
    p += (bytes + 255) & ~(size_t)255;
    return r;
  };
  unsigned short* hbuf  = (unsigned short*)take((size_t)NTOK * D_MODEL * 2);
  unsigned short* wqkvT = (unsigned short*)take((size_t)2304 * 768 * 2);
  unsigned short* woT   = (unsigned short*)take((size_t)768 * 768 * 2);
  unsigned short* w1T   = (unsigned short*)take((size_t)3072 * 768 * 2);
  unsigned short* w2T   = (unsigned short*)take((size_t)768 * 3072 * 2);
  unsigned short* qbuf  = (unsigned short*)take((size_t)8 * NH * SEQ * DHD * 2);
  unsigned short* kbuf  = (unsigned short*)take((size_t)8 * NH * SEQ * DHD * 2);
  unsigned short* vtbuf = (unsigned short*)take((size_t)8 * NH * SEQ * DHD * 2);
  unsigned short* ctxb  = (unsigned short*)take((size_t)NTOK * D_MODEL * 2);
  unsigned short* h1buf = (unsigned short*)take((size_t)NTOK * DFF * 2);
  // x2 (post-attention residual stream) lives in d_out (fp32).

  // weight prep (independent of activations)
  wtrans_kernel<<<dim3(2304 / 32, 768 / 32), 256, 0, stream>>>(wqkv, wqkvT, 768, 2304);
  wtrans_kernel<<<dim3(768 / 32, 768 / 32), 256, 0, stream>>>(wo, woT, 768, 768);
  wtrans_kernel<<<dim3(3072 / 32, 768 / 32), 256, 0, stream>>>(w1, w1T, 768, 3072);
  wtrans_kernel<<<dim3(768 / 32, 3072 / 32), 256, 0, stream>>>(w2, w2T, 3072, 768);

  // LN1: x -> h (bf16)
  ln_kernel<<<NTOK / 4, 256, 0, stream>>>(x, ln1_g, ln1_b, hbuf);
  // QKV: h @ wqkv + bqkv -> q,k,Vt (bf16, attention layouts)
  gemm_bt<MODE_QKV><<<dim3(2304 / 128, NTOK / 128), 256, 0, stream>>>(
      hbuf, wqkvT, 768, bqkv, nullptr, nullptr, qbuf, kbuf, vtbuf);
  // attention -> ctx (bf16, [tok][D])
  attn_kernel<<<8 * NH * (SEQ / 64), 256, 0, stream>>>(qbuf, kbuf, vtbuf, rel, ctxb);
  // proj: ctx @ wo + bo + x -> x2 (fp32, in d_out)
  gemm_bt<MODE_PROJ><<<dim3(768 / 128, NTOK / 128), 256, 0, stream>>>(
      ctxb, woT, 768, bo, x, out, nullptr, nullptr, nullptr);
  // LN2: x2 -> h2 (bf16, reuse hbuf)
  ln_kernel<<<NTOK / 4, 256, 0, stream>>>(out, ln2_g, ln2_b, hbuf);
  // FFN1: h2 @ w1 + b1, gelu -> h1 (bf16)
  gemm_bt<MODE_FFN1><<<dim3(DFF / 128, NTOK / 128), 256, 0, stream>>>(
      hbuf, w1T, 768, b1, nullptr, nullptr, h1buf, nullptr, nullptr);
  // FFN2: h1 @ w2 + b2 + x2 -> out (fp32, in place on d_out)
  gemm_bt<MODE_FFN2><<<dim3(768 / 128, NTOK / 128), 256, 0, stream>>>(
      h1buf, w2T, 3072, b2, out, out, nullptr, nullptr, nullptr);
}

// Round 4
// 331.902 us; speedup vs baseline: 1.4312x; 1.4087x over previous
//
#include <hip/hip_runtime.h>
#include <hip/hip_bf16.h>
#include <math.h>

#define D_MODEL 768
#define NTOK    8192   // B*N
#define SEQ     1024
#define NH      12
#define DHD     64
#define DFF     3072

typedef __attribute__((ext_vector_type(8)))  __bf16 bf16x8;
typedef __attribute__((ext_vector_type(4)))  float  f32x4;
typedef __attribute__((ext_vector_type(16))) float  f32x16;
typedef __attribute__((ext_vector_type(4)))  unsigned short us4;

typedef const __attribute__((address_space(1))) void g_void;
typedef __attribute__((address_space(3))) void lds_void;

__device__ __forceinline__ unsigned short f2bf(float f) {
  unsigned u = __float_as_uint(f);
  u += 0x7fffu + ((u >> 16) & 1u);   // RNE to bf16
  return (unsigned short)(u >> 16);
}

__device__ __forceinline__ f32x4 mfma16(bf16x8 a, bf16x8 b, f32x4 c) {
  return __builtin_amdgcn_mfma_f32_16x16x32_bf16(a, b, c, 0, 0, 0);
}
__device__ __forceinline__ f32x16 mfma32(bf16x8 a, bf16x8 b, f32x16 c) {
  return __builtin_amdgcn_mfma_f32_32x32x16_bf16(a, b, c, 0, 0, 0);
}

// async global->LDS, 16B per lane; LDS dest = uniform base + lane*16
__device__ __forceinline__ void gload_lds16(const unsigned short* g, unsigned short* l) {
  __builtin_amdgcn_global_load_lds((g_void*)g, (lds_void*)l, 16, 0, 0);
}

// ---------------- LayerNorm: one wave per row of 768, fp32 in -> bf16 out ----
__global__ __launch_bounds__(256)
void ln_kernel(const float* __restrict__ x, const float* __restrict__ gam,
               const float* __restrict__ bet, unsigned short* __restrict__ out) {
  const int w = threadIdx.x >> 6, lane = threadIdx.x & 63;
  const size_t row = (size_t)blockIdx.x * 4 + w;
  const float* xr = x + row * D_MODEL;
  f32x4 v[3];
#pragma unroll
  for (int c = 0; c < 3; ++c) v[c] = *(const f32x4*)(xr + c * 256 + lane * 4);
  float s = 0.f;
#pragma unroll
  for (int c = 0; c < 3; ++c)
#pragma unroll
    for (int j = 0; j < 4; ++j) s += v[c][j];
#pragma unroll
  for (int o = 32; o; o >>= 1) s += __shfl_xor(s, o);
  const float mu = s * (1.0f / D_MODEL);
  float vs = 0.f;
#pragma unroll
  for (int c = 0; c < 3; ++c)
#pragma unroll
    for (int j = 0; j < 4; ++j) { float d = v[c][j] - mu; vs += d * d; }
#pragma unroll
  for (int o = 32; o; o >>= 1) vs += __shfl_xor(vs, o);
  const float rs = rsqrtf(vs * (1.0f / D_MODEL) + 1e-5f);
  unsigned short* orow = out + row * D_MODEL;
#pragma unroll
  for (int c = 0; c < 3; ++c) {
    us4 o4;
#pragma unroll
    for (int j = 0; j < 4; ++j) {
      int idx = c * 256 + lane * 4 + j;
      o4[j] = f2bf((v[c][j] - mu) * rs * gam[idx] + bet[idx]);
    }
    *(us4*)(orow + c * 256 + lane * 4) = o4;
  }
}

// ------------- weight transpose + cast: W[K][Nc] f32 -> Wt[Nc][K] bf16 -------
__global__ __launch_bounds__(256)
void wtrans_kernel(const float* __restrict__ W, unsigned short* __restrict__ Wt,
                   int K, int Nc) {
  __shared__ float t[32][33];
  const int tx = threadIdx.x & 31, ty = threadIdx.x >> 5;  // 32x8
  const int nb = blockIdx.x * 32, kb = blockIdx.y * 32;
#pragma unroll
  for (int i = 0; i < 4; ++i)
    t[ty + 8 * i][tx] = W[(size_t)(kb + ty + 8 * i) * Nc + nb + tx];
  __syncthreads();
#pragma unroll
  for (int i = 0; i < 4; ++i)
    Wt[(size_t)(nb + ty + 8 * i) * K + kb + tx] = f2bf(t[tx][ty + 8 * i]);
}

// ------ bias reshape: rel[H][N][N] f32 -> biasF[h][qt32][kt32][lane][16] bf16
// Fragment order of the 32x32 S^T tile: lane l covers q = qt*32+(l&31);
// reg r covers k = kt*32 + (r&3) + 8*(r>>2) + 4*(l>>5). Packed (r0,r1)(r2,r3)..
__global__ __launch_bounds__(256)
void brelayout_kernel(const float* __restrict__ rel, unsigned short* __restrict__ bF) {
  const int gw = blockIdx.x * 4 + (threadIdx.x >> 6);  // (h*32+qt)*32+ktg
  const int lane = threadIdx.x & 63;
  const int ktg = gw & 31, qt = (gw >> 5) & 31, h = gw >> 10;
  const int q = qt * 32 + (lane & 31), hi = lane >> 5;
  const float* src = rel + ((size_t)h * SEQ + q) * SEQ + ktg * 32 + 4 * hi;
  unsigned ow[8];
#pragma unroll
  for (int g = 0; g < 4; ++g) {
    f32x4 v = *(const f32x4*)(src + g * 8);
    asm("v_cvt_pk_bf16_f32 %0, %1, %2" : "=v"(ow[2 * g])     : "v"(v[0]), "v"(v[1]));
    asm("v_cvt_pk_bf16_f32 %0, %1, %2" : "=v"(ow[2 * g + 1]) : "v"(v[2]), "v"(v[3]));
  }
  unsigned short* dst = bF + (((size_t)gw) * 64 + lane) * 16;
  *(uint4*)(dst)     = make_uint4(ow[0], ow[1], ow[2], ow[3]);
  *(uint4*)(dst + 8) = make_uint4(ow[4], ow[5], ow[6], ow[7]);
}

// ---------------- GEMM: C[M][N] = A[M][K] @ Bt[N][K]^T, bf16 in, fused epilogue
#define MODE_QKV  0
#define MODE_PROJ 1
#define MODE_FFN1 2
#define MODE_FFN2 3

template <int MODE>
__global__ __launch_bounds__(256)
void gemm_bt(const unsigned short* __restrict__ A, const unsigned short* __restrict__ Bt,
             int K, const float* __restrict__ bias, const float* __restrict__ resid,
             float* __restrict__ outF, unsigned short* __restrict__ o0,
             unsigned short* __restrict__ o1, unsigned short* __restrict__ o2) {
  __shared__ alignas(16) unsigned short sA[2][128 * 32];
  __shared__ alignas(16) unsigned short sB[2][128 * 32];
  const int tid = threadIdx.x;
  const int w = tid >> 6, lane = tid & 63;
  const int lr = lane & 15, lg = lane >> 4;
  const int wm = w >> 1, wn = w & 1;
  const size_t m0 = (size_t)blockIdx.y * 128;
  const size_t n0 = (size_t)blockIdx.x * 128;
  const unsigned short* gA = A + m0 * K;
  const unsigned short* gB = Bt + n0 * K;
  const int srow = lane >> 2;        // 0..15: row within 16-row chunk
  const int scol = (lane & 3) * 8;   // element col within 32-wide row

  f32x4 acc[4][4] = {};
  const int nk = K >> 5;

  auto stage = [&](int buf, int kt) {
#pragma unroll
    for (int i = 0; i < 2; ++i) {
      const int r = w * 32 + i * 16;
      gload_lds16(gA + (size_t)(r + srow) * K + kt * 32 + scol, &sA[buf][r * 32]);
      gload_lds16(gB + (size_t)(r + srow) * K + kt * 32 + scol, &sB[buf][r * 32]);
    }
  };

  stage(0, 0);
  __syncthreads();
  int cur = 0;
  for (int kt = 0; kt < nk; ++kt) {
    if (kt + 1 < nk) stage(cur ^ 1, kt + 1);
    bf16x8 af[4], bfr[4];
#pragma unroll
    for (int i = 0; i < 4; ++i) {
      af[i]  = *(const bf16x8*)&sA[cur][(wm * 64 + i * 16 + lr) * 32 + lg * 8];
      bfr[i] = *(const bf16x8*)&sB[cur][(wn * 64 + i * 16 + lr) * 32 + lg * 8];
    }
#pragma unroll
    for (int i = 0; i < 4; ++i)
#pragma unroll
      for (int j = 0; j < 4; ++j) acc[i][j] = mfma16(af[i], bfr[j], acc[i][j]);
    __syncthreads();   // drains vmcnt (next-tile staging) + closes read phase
    cur ^= 1;
  }

#pragma unroll
  for (int i = 0; i < 4; ++i) {
#pragma unroll
    for (int j = 0; j < 4; ++j) {
#pragma unroll
      for (int r = 0; r < 4; ++r) {
        const int m = (int)m0 + wm * 64 + i * 16 + lg * 4 + r;
        const int n = (int)n0 + wn * 64 + j * 16 + lr;
        float v = acc[i][j][r] + bias[n];
        if constexpr (MODE == MODE_QKV) {
          const int b = m >> 10, nq = m & 1023;
          if (n < 768) {
            const int h = n >> 6, dh = n & 63;
            o0[(((size_t)(b * NH + h)) * SEQ + nq) * DHD + dh] = f2bf(v);
          } else if (n < 1536) {
            const int n2 = n - 768, h = n2 >> 6, dh = n2 & 63;
            o1[(((size_t)(b * NH + h)) * SEQ + nq) * DHD + dh] = f2bf(v);
          } else {
            const int n2 = n - 1536, h = n2 >> 6, dh = n2 & 63;
            o2[(((size_t)(b * NH + h)) * DHD + dh) * SEQ + nq] = f2bf(v);  // V^T
          }
        } else if constexpr (MODE == MODE_PROJ) {
          const size_t off = (size_t)m * D_MODEL + n;
          outF[off] = v + resid[off];
        } else if constexpr (MODE == MODE_FFN1) {
          const float g3 = v * v * v;
          const float gl = 0.5f * v * (1.0f + tanhf(0.7978845608028654f * (v + 0.044715f * g3)));
          o0[(size_t)m * DFF + n] = f2bf(gl);
        } else {  // FFN2: in-place residual on outF (x2 lives there)
          const size_t off = (size_t)m * D_MODEL + n;
          outF[off] = v + resid[off];
        }
      }
    }
  }
}

// ------- fused flash attention: 4 waves x 32 q-rows, 32x32x16 MFMA ----------
// K/V staged into LDS in fragment order (shared by all 4 waves); swapped
// operands: S^T[k][q] = mfma(K,Q) so q = lane&31, k = reg-mapped; softmax
// fully in-lane with defer-max; P via wave-private LDS round-trip.
__global__ __launch_bounds__(256, 3)
void attn_kernel(const unsigned short* __restrict__ q, const unsigned short* __restrict__ k,
                 const unsigned short* __restrict__ vt, const unsigned short* __restrict__ bF,
                 unsigned short* __restrict__ ctx) {
  // kv slots: [buf][slot 0..15][64 lanes * 8 shorts]; slots 0-7 = K (kt*4+ds),
  // slots 8-15 = V (8 + dt*4 + kh). Each slot = one ds_read_b128 fragment set.
  __shared__ alignas(16) unsigned short kv[2][16][64 * 8];
  constexpr int PSTR = 76;  // shorts; 152B row: 2-way max bank aliasing (free)
  __shared__ alignas(16) unsigned short pbuf[4][32 * PSTR];
  const int tid = threadIdx.x, w = tid >> 6, lane = tid & 63;
  const int l31 = lane & 31, hi = lane >> 5;
  // XCD-chunked swizzle (768 % 8 == 0 -> bijective): 12 bh per XCD, K/V L2-res.
  const int bid = (blockIdx.x & 7) * 96 + (blockIdx.x >> 3);
  const int bh = bid >> 3, qblk = bid & 7;
  const int b = bh / NH, h = bh % NH;
  const int q0w = qblk * 128 + w * 32;
  const unsigned short* qp = q + (size_t)bh * SEQ * DHD;
  const unsigned short* kp = k + (size_t)bh * SEQ * DHD;
  const unsigned short* vp = vt + (size_t)bh * DHD * SEQ;
  // bias fragment stream for this wave's 32 q-rows (qt = qblk*4 + w)
  const unsigned short* bfp = bF + ((((size_t)(h * 32 + qblk * 4 + w)) * 32) * 64 + lane) * 16;

  // Q B-fragments (kept all kernel): col q = l31, d = ds*16 + hi*8 + e
  bf16x8 Qf[4];
#pragma unroll
  for (int ds = 0; ds < 4; ++ds)
    Qf[ds] = *(const bf16x8*)(qp + (size_t)(q0w + l31) * DHD + ds * 16 + hi * 8);

  f32x16 o[2];
#pragma unroll
  for (int dt = 0; dt < 2; ++dt) o[dt] = (f32x16)(0.f);
  float mrun = -INFINITY, lrun = 0.f;
  const float scale = 0.125f;  // 1/sqrt(64)
  unsigned short* pw = pbuf[w];

  auto stage = [&](int buf, int kb) {
    if (w < 2) {  // K slots: kt = w, ds 0..3; lane = A-frag row k, cols d
      const unsigned short* g0 = kp + (size_t)(kb * 64 + w * 32 + l31) * DHD + hi * 8;
#pragma unroll
      for (int ds = 0; ds < 4; ++ds)
        gload_lds16(g0 + ds * 16, &kv[buf][w * 4 + ds][0]);
    } else {      // V slots: dt = w-2, kh 0..3; lane = A-frag row d, cols k
      const int dt = w - 2;
      const unsigned short* g0 = vp + (size_t)(dt * 32 + l31) * SEQ + kb * 64 + hi * 8;
#pragma unroll
      for (int kh = 0; kh < 4; ++kh)
        gload_lds16(g0 + kh * 16, &kv[buf][8 + dt * 4 + kh][0]);
    }
  };

  stage(0, 0);
  __syncthreads();
  for (int kb = 0; kb < SEQ / 64; ++kb) {
    const int buf = kb & 1;
    if (kb + 1 < SEQ / 64) stage(buf ^ 1, kb + 1);

    // ---- S^T for 64 keys: 2 kt-tiles x 4 d-slices
    f32x16 s0 = (f32x16)(0.f), s1 = (f32x16)(0.f);
    __builtin_amdgcn_s_setprio(1);
#pragma unroll
    for (int ds = 0; ds < 4; ++ds) {
      bf16x8 kf0 = *(const bf16x8*)&kv[buf][ds][lane * 8];
      s0 = mfma32(kf0, Qf[ds], s0);
      bf16x8 kf1 = *(const bf16x8*)&kv[buf][4 + ds][lane * 8];
      s1 = mfma32(kf1, Qf[ds], s1);
    }
    __builtin_amdgcn_s_setprio(0);

    // ---- bias add (bf16 fragment stream, coalesced)
    const unsigned short* bb = bfp + (size_t)(kb * 2) * 64 * 16;
    uint4 a0 = *(const uint4*)(bb),            a1 = *(const uint4*)(bb + 8);
    uint4 c0 = *(const uint4*)(bb + 64 * 16),  c1 = *(const uint4*)(bb + 64 * 16 + 8);
    unsigned uw0[8] = {a0.x, a0.y, a0.z, a0.w, a1.x, a1.y, a1.z, a1.w};
    unsigned uw1[8] = {c0.x, c0.y, c0.z, c0.w, c1.x, c1.y, c1.z, c1.w};
    float p0[16], p1[16];
#pragma unroll
    for (int j = 0; j < 8; ++j) {
      p0[2 * j]     = fmaf(s0[2 * j],     scale, __uint_as_float(uw0[j] << 16));
      p0[2 * j + 1] = fmaf(s0[2 * j + 1], scale, __uint_as_float(uw0[j] & 0xffff0000u));
      p1[2 * j]     = fmaf(s1[2 * j],     scale, __uint_as_float(uw1[j] << 16));
      p1[2 * j + 1] = fmaf(s1[2 * j + 1], scale, __uint_as_float(uw1[j] & 0xffff0000u));
    }

    // ---- softmax (defer-max): in-lane max over 32, cross-pair only on rescale
    float pmax = p0[0];
#pragma unroll
    for (int i = 1; i < 16; ++i) pmax = fmaxf(pmax, p0[i]);
#pragma unroll
    for (int i = 0; i < 16; ++i) pmax = fmaxf(pmax, p1[i]);
    if (!__all(pmax - mrun <= 8.0f)) {
      float pm = fmaxf(pmax, __shfl_xor(pmax, 32));
      const float mn = fmaxf(mrun, pm);
      const float al = __expf(mrun - mn);
      mrun = mn;
      lrun *= al;
#pragma unroll
      for (int dt = 0; dt < 2; ++dt)
#pragma unroll
        for (int r = 0; r < 16; ++r) o[dt][r] *= al;
    }
#pragma unroll
    for (int i = 0; i < 16; ++i) { p0[i] = __expf(p0[i] - mrun); lrun += p0[i]; }
#pragma unroll
    for (int i = 0; i < 16; ++i) { p1[i] = __expf(p1[i] - mrun); lrun += p1[i]; }

    // ---- pack P -> bf16, write P^T[q][64] (wave-private), read B-frags
#pragma unroll
    for (int g = 0; g < 4; ++g) {
      uint2 w0, w1;
      asm("v_cvt_pk_bf16_f32 %0, %1, %2" : "=v"(w0.x) : "v"(p0[4 * g]),     "v"(p0[4 * g + 1]));
      asm("v_cvt_pk_bf16_f32 %0, %1, %2" : "=v"(w0.y) : "v"(p0[4 * g + 2]), "v"(p0[4 * g + 3]));
      asm("v_cvt_pk_bf16_f32 %0, %1, %2" : "=v"(w1.x) : "v"(p1[4 * g]),     "v"(p1[4 * g + 1]));
      asm("v_cvt_pk_bf16_f32 %0, %1, %2" : "=v"(w1.y) : "v"(p1[4 * g + 2]), "v"(p1[4 * g + 3]));
      // quad g of kt-tile covers k = kt*32 + g*8 + 4*hi + {0..3}
      *(uint2*)(pw + l31 * PSTR +      g * 8 + 4 * hi) = w0;
      *(uint2*)(pw + l31 * PSTR + 32 + g * 8 + 4 * hi) = w1;
    }
    bf16x8 pf[4];
#pragma unroll
    for (int kh = 0; kh < 4; ++kh)
      pf[kh] = *(const bf16x8*)(pw + l31 * PSTR + kh * 16 + hi * 8);

    // ---- PV: O^T[d][q] += V^T-frag x P-frag
    __builtin_amdgcn_s_setprio(1);
#pragma unroll
    for (int dt = 0; dt < 2; ++dt)
#pragma unroll
      for (int kh = 0; kh < 4; ++kh) {
        bf16x8 vf = *(const bf16x8*)&kv[buf][8 + dt * 4 + kh][lane * 8];
        o[dt] = mfma32(vf, pf[kh], o[dt]);
      }
    __builtin_amdgcn_s_setprio(0);

    __syncthreads();  // staging of buf^1 complete + all waves done with buf
  }

  lrun += __shfl_xor(lrun, 32);
  const float inv = 1.0f / lrun;
  // O^T reg r: d = dt*32 + (r&3) + 8*(r>>2) + 4*hi, q = l31
  unsigned short* crow = ctx + ((size_t)b * SEQ + q0w + l31) * D_MODEL + h * DHD;
#pragma unroll
  for (int dt = 0; dt < 2; ++dt)
#pragma unroll
    for (int g = 0; g < 4; ++g) {
      us4 ov;
#pragma unroll
      for (int j = 0; j < 4; ++j) ov[j] = f2bf(o[dt][4 * g + j] * inv);
      *(us4*)(crow + dt * 32 + g * 8 + 4 * hi) = ov;
    }
}

// ----------------------------------------------------------------------------
extern "C" void kernel_launch(void* const* d_in, const int* in_sizes, int n_in,
                              void* d_out, int out_size, void* d_ws, size_t ws_size,
                              hipStream_t stream) {
  (void)in_sizes; (void)n_in; (void)out_size; (void)ws_size;
  const float* x     = (const float*)d_in[0];
  const float* ln1_g = (const float*)d_in[1];
  const float* ln1_b = (const float*)d_in[2];
  const float* wqkv  = (const float*)d_in[3];
  const float* bqkv  = (const float*)d_in[4];
  const float* wo    = (const float*)d_in[5];
  const float* bo    = (const float*)d_in[6];
  const float* rel   = (const float*)d_in[7];
  const float* ln2_g = (const float*)d_in[8];
  const float* ln2_b = (const float*)d_in[9];
  const float* w1    = (const float*)d_in[10];
  const float* b1    = (const float*)d_in[11];
  const float* w2    = (const float*)d_in[12];
  const float* b2    = (const float*)d_in[13];
  float* out = (float*)d_out;

  char* p = (char*)d_ws;
  auto take = [&](size_t bytes) {
    void* r = (void*)p;
    p += (bytes + 255) & ~(size_t)255;
    return r;
  };
  unsigned short* hbuf  = (unsigned short*)take((size_t)NTOK * D_MODEL * 2);
  unsigned short* wqkvT = (unsigned short*)take((size_t)2304 * 768 * 2);
  unsigned short* woT   = (unsigned short*)take((size_t)768 * 768 * 2);
  unsigned short* w1T   = (unsigned short*)take((size_t)3072 * 768 * 2);
  unsigned short* w2T   = (unsigned short*)take((size_t)768 * 3072 * 2);
  unsigned short* qbuf  = (unsigned short*)take((size_t)8 * NH * SEQ * DHD * 2);
  unsigned short* kbuf  = (unsigned short*)take((size_t)8 * NH * SEQ * DHD * 2);
  unsigned short* vtbuf = (unsigned short*)take((size_t)8 * NH * SEQ * DHD * 2);
  unsigned short* ctxb  = (unsigned short*)take((size_t)NTOK * D_MODEL * 2);
  unsigned short* h1buf = (unsigned short*)take((size_t)NTOK * DFF * 2);
  // biasF (25.2 MB) aliases h1buf (50.3 MB): dead before FFN1 writes h1buf.
  unsigned short* biasF = h1buf;
  // x2 (post-attention residual stream) lives in d_out (fp32).

  // weight prep (independent of activations)
  wtrans_kernel<<<dim3(2304 / 32, 768 / 32), 256, 0, stream>>>(wqkv, wqkvT, 768, 2304);
  wtrans_kernel<<<dim3(768 / 32, 768 / 32), 256, 0, stream>>>(wo, woT, 768, 768);
  wtrans_kernel<<<dim3(3072 / 32, 768 / 32), 256, 0, stream>>>(w1, w1T, 768, 3072);
  wtrans_kernel<<<dim3(768 / 32, 3072 / 32), 256, 0, stream>>>(w2, w2T, 3072, 768);
  // bias -> bf16 fragment order
  brelayout_kernel<<<NH * 32 * 32 / 4, 256, 0, stream>>>(rel, biasF);

  // LN1: x -> h (bf16)
  ln_kernel<<<NTOK / 4, 256, 0, stream>>>(x, ln1_g, ln1_b, hbuf);
  // QKV: h @ wqkv + bqkv -> q,k,Vt (bf16, attention layouts)
  gemm_bt<MODE_QKV><<<dim3(2304 / 128, NTOK / 128), 256, 0, stream>>>(
      hbuf, wqkvT, 768, bqkv, nullptr, nullptr, qbuf, kbuf, vtbuf);
  // attention -> ctx (bf16, [tok][D])
  attn_kernel<<<8 * NH * (SEQ / 128), 256, 0, stream>>>(qbuf, kbuf, vtbuf, biasF, ctxb);
  // proj: ctx @ wo + bo + x -> x2 (fp32, in d_out)
  gemm_bt<MODE_PROJ><<<dim3(768 / 128, NTOK / 128), 256, 0, stream>>>(
      ctxb, woT, 768, bo, x, out, nullptr, nullptr, nullptr);
  // LN2: x2 -> h2 (bf16, reuse hbuf)
  ln_kernel<<<NTOK / 4, 256, 0, stream>>>(out, ln2_g, ln2_b, hbuf);
  // FFN1: h2 @ w1 + b1, gelu -> h1 (bf16)
  gemm_bt<MODE_FFN1><<<dim3(DFF / 128, NTOK / 128), 256, 0, stream>>>(
      hbuf, w1T, 768, b1, nullptr, nullptr, h1buf, nullptr, nullptr);
  // FFN2: h1 @ w2 + b2 + x2 -> out (fp32, in place on d_out)
  gemm_bt<MODE_FFN2><<<dim3(768 / 128, NTOK / 128), 256, 0, stream>>>(
      h1buf, w2T, 3072, b2, out, out, nullptr, nullptr, nullptr);
}

// Round 5
// 321.181 us; speedup vs baseline: 1.4790x; 1.0334x over previous
//
#include <hip/hip_runtime.h>
#include <hip/hip_bf16.h>
#include <math.h>

#define D_MODEL 768
#define NTOK    8192   // B*N
#define SEQ     1024
#define NH      12
#define DHD     64
#define DFF     3072

typedef __attribute__((ext_vector_type(8)))  __bf16 bf16x8;
typedef __attribute__((ext_vector_type(4)))  float  f32x4;
typedef __attribute__((ext_vector_type(16))) float  f32x16;
typedef __attribute__((ext_vector_type(4)))  unsigned short us4;

typedef const __attribute__((address_space(1))) void g_void;
typedef __attribute__((address_space(3))) void lds_void;

__device__ __forceinline__ unsigned short f2bf(float f) {
  unsigned u = __float_as_uint(f);
  u += 0x7fffu + ((u >> 16) & 1u);   // RNE to bf16
  return (unsigned short)(u >> 16);
}

__device__ __forceinline__ f32x4 mfma16(bf16x8 a, bf16x8 b, f32x4 c) {
  return __builtin_amdgcn_mfma_f32_16x16x32_bf16(a, b, c, 0, 0, 0);
}
__device__ __forceinline__ f32x16 mfma32(bf16x8 a, bf16x8 b, f32x16 c) {
  return __builtin_amdgcn_mfma_f32_32x32x16_bf16(a, b, c, 0, 0, 0);
}

// async global->LDS, 16B per lane; LDS dest = uniform base + lane*16
__device__ __forceinline__ void gload_lds16(const unsigned short* g, unsigned short* l) {
  __builtin_amdgcn_global_load_lds((g_void*)g, (lds_void*)l, 16, 0, 0);
}

// ---------------- LayerNorm: one wave per row of 768, fp32 in -> bf16 out ----
__global__ __launch_bounds__(256)
void ln_kernel(const float* __restrict__ x, const float* __restrict__ gam,
               const float* __restrict__ bet, unsigned short* __restrict__ out) {
  const int w = threadIdx.x >> 6, lane = threadIdx.x & 63;
  const size_t row = (size_t)blockIdx.x * 4 + w;
  const float* xr = x + row * D_MODEL;
  f32x4 v[3];
#pragma unroll
  for (int c = 0; c < 3; ++c) v[c] = *(const f32x4*)(xr + c * 256 + lane * 4);
  float s = 0.f;
#pragma unroll
  for (int c = 0; c < 3; ++c)
#pragma unroll
    for (int j = 0; j < 4; ++j) s += v[c][j];
#pragma unroll
  for (int o = 32; o; o >>= 1) s += __shfl_xor(s, o);
  const float mu = s * (1.0f / D_MODEL);
  float vs = 0.f;
#pragma unroll
  for (int c = 0; c < 3; ++c)
#pragma unroll
    for (int j = 0; j < 4; ++j) { float d = v[c][j] - mu; vs += d * d; }
#pragma unroll
  for (int o = 32; o; o >>= 1) vs += __shfl_xor(vs, o);
  const float rs = rsqrtf(vs * (1.0f / D_MODEL) + 1e-5f);
  unsigned short* orow = out + row * D_MODEL;
#pragma unroll
  for (int c = 0; c < 3; ++c) {
    us4 o4;
#pragma unroll
    for (int j = 0; j < 4; ++j) {
      int idx = c * 256 + lane * 4 + j;
      o4[j] = f2bf((v[c][j] - mu) * rs * gam[idx] + bet[idx]);
    }
    *(us4*)(orow + c * 256 + lane * 4) = o4;
  }
}

// ------------- weight transpose + cast: W[K][Nc] f32 -> Wt[Nc][K] bf16 -------
__global__ __launch_bounds__(256)
void wtrans_kernel(const float* __restrict__ W, unsigned short* __restrict__ Wt,
                   int K, int Nc) {
  __shared__ float t[32][33];
  const int tx = threadIdx.x & 31, ty = threadIdx.x >> 5;  // 32x8
  const int nb = blockIdx.x * 32, kb = blockIdx.y * 32;
#pragma unroll
  for (int i = 0; i < 4; ++i)
    t[ty + 8 * i][tx] = W[(size_t)(kb + ty + 8 * i) * Nc + nb + tx];
  __syncthreads();
#pragma unroll
  for (int i = 0; i < 4; ++i)
    Wt[(size_t)(nb + ty + 8 * i) * K + kb + tx] = f2bf(t[tx][ty + 8 * i]);
}

// ------ bias reshape: rel[H][N][N] f32 -> biasF[h][qt32][kt32][lane][16] bf16
// Fragment order of the 32x32 S^T tile: lane l covers q = qt*32+(l&31);
// reg r covers k = kt*32 + (r&3) + 8*(r>>2) + 4*(l>>5). Packed (r0,r1)(r2,r3)..
__global__ __launch_bounds__(256)
void brelayout_kernel(const float* __restrict__ rel, unsigned short* __restrict__ bF) {
  const int gw = blockIdx.x * 4 + (threadIdx.x >> 6);  // (h*32+qt)*32+ktg
  const int lane = threadIdx.x & 63;
  const int ktg = gw & 31, qt = (gw >> 5) & 31, h = gw >> 10;
  const int q = qt * 32 + (lane & 31), hi = lane >> 5;
  const float* src = rel + ((size_t)h * SEQ + q) * SEQ + ktg * 32 + 4 * hi;
  unsigned ow[8];
#pragma unroll
  for (int g = 0; g < 4; ++g) {
    f32x4 v = *(const f32x4*)(src + g * 8);
    asm("v_cvt_pk_bf16_f32 %0, %1, %2" : "=v"(ow[2 * g])     : "v"(v[0]), "v"(v[1]));
    asm("v_cvt_pk_bf16_f32 %0, %1, %2" : "=v"(ow[2 * g + 1]) : "v"(v[2]), "v"(v[3]));
  }
  unsigned short* dst = bF + (((size_t)gw) * 64 + lane) * 16;
  *(uint4*)(dst)     = make_uint4(ow[0], ow[1], ow[2], ow[3]);
  *(uint4*)(dst + 8) = make_uint4(ow[4], ow[5], ow[6], ow[7]);
}

// -------- GEMM: C[M][N] = A[M][K] @ Bt[N][K]^T, bf16, fused epilogue --------
// 128x128 tile, BK=64, 4 waves (wave tile 64x64 = 2x2 of 32x32x16 MFMA).
// LDS XOR-swizzle (unit ^= row&7 on 16B units within 128B rows), applied on
// the per-lane GLOBAL source (gload_lds dest stays linear) and on ds_read col.
#define MODE_QKV  0
#define MODE_PROJ 1
#define MODE_FFN1 2
#define MODE_FFN2 3

template <int MODE>
__global__ __launch_bounds__(256)
void gemm_bt(const unsigned short* __restrict__ A, const unsigned short* __restrict__ Bt,
             int K, const float* __restrict__ bias, const float* __restrict__ resid,
             float* __restrict__ outF, unsigned short* __restrict__ o0,
             unsigned short* __restrict__ o1, unsigned short* __restrict__ o2) {
  __shared__ alignas(16) unsigned short sA[2][128 * 64];
  __shared__ alignas(16) unsigned short sB[2][128 * 64];
  const int tid = threadIdx.x;
  const int w = tid >> 6, lane = tid & 63;
  const int l31 = lane & 31, hi = lane >> 5;
  const int wm = w >> 1, wn = w & 1;
  // XCD-chunked bijective swizzle (all grids are multiples of 8 blocks)
  const int nwg = gridDim.x * gridDim.y;
  const int bid0 = blockIdx.y * gridDim.x + blockIdx.x;
  const int cpx = nwg >> 3;
  const int bid = (bid0 & 7) * cpx + (bid0 >> 3);
  const int bx = bid % gridDim.x, by = bid / gridDim.x;
  const size_t m0 = (size_t)by * 128;
  const size_t n0 = (size_t)bx * 128;
  const unsigned short* gA = A + m0 * K;
  const unsigned short* gB = Bt + n0 * K;

  // staging decomposition: lane -> (row-in-8-group, 16B unit), source col XOR'd
  const int r8 = lane >> 3;         // 0..7
  const int u8 = lane & 7;          // 16B unit 0..7 within 128B row
  const int ucol = (u8 ^ r8) * 8;   // swizzled element offset within BK=64 row

  f32x16 acc[2][2];
#pragma unroll
  for (int i = 0; i < 2; ++i)
#pragma unroll
    for (int j = 0; j < 2; ++j) acc[i][j] = (f32x16)(0.f);
  const int nk = K >> 6;

  auto stage = [&](int buf, int kt) {
#pragma unroll
    for (int g = 0; g < 4; ++g) {
      const int rowb = w * 32 + g * 8;  // wave-uniform base row (multiple of 8)
      gload_lds16(gA + (size_t)(rowb + r8) * K + kt * 64 + ucol, &sA[buf][rowb * 64]);
      gload_lds16(gB + (size_t)(rowb + r8) * K + kt * 64 + ucol, &sB[buf][rowb * 64]);
    }
  };

  // frag read offsets: row = base + l31 (base % 8 == 0), unit j = ks*2 + hi
  const int swr = l31 & 7;
  const int rA = (wm * 64 + l31) * 64;
  const int rB = (wn * 64 + l31) * 64;

  stage(0, 0);
  __syncthreads();
  for (int kt = 0; kt < nk; ++kt) {
    const int buf = kt & 1;
    if (kt + 1 < nk) stage(buf ^ 1, kt + 1);
    bf16x8 af[2][4], bf[2][4];
#pragma unroll
    for (int mt = 0; mt < 2; ++mt)
#pragma unroll
      for (int ks = 0; ks < 4; ++ks) {
        af[mt][ks] = *(const bf16x8*)&sA[buf][rA + mt * 2048 + (((ks * 2 + hi) ^ swr) * 8)];
        bf[mt][ks] = *(const bf16x8*)&sB[buf][rB + mt * 2048 + (((ks * 2 + hi) ^ swr) * 8)];
      }
#pragma unroll
    for (int mt = 0; mt < 2; ++mt)
#pragma unroll
      for (int nt = 0; nt < 2; ++nt)
#pragma unroll
        for (int ks = 0; ks < 4; ++ks)
          acc[mt][nt] = mfma32(af[mt][ks], bf[nt][ks], acc[mt][nt]);
    __syncthreads();   // staging of buf^1 complete + all waves done reading buf
  }

  // epilogue: 32x32 C/D map: n = tile + l31, m = tile + (r&3) + 8*(r>>2) + 4*hi
#pragma unroll
  for (int mt = 0; mt < 2; ++mt) {
#pragma unroll
    for (int nt = 0; nt < 2; ++nt) {
#pragma unroll
      for (int r = 0; r < 16; ++r) {
        const int m = (int)m0 + wm * 64 + mt * 32 + (r & 3) + 8 * (r >> 2) + 4 * hi;
        const int n = (int)n0 + wn * 64 + nt * 32 + l31;
        float v = acc[mt][nt][r] + bias[n];
        if constexpr (MODE == MODE_QKV) {
          const int b = m >> 10, nq = m & 1023;
          if (n < 768) {
            const int h = n >> 6, dh = n & 63;
            o0[(((size_t)(b * NH + h)) * SEQ + nq) * DHD + dh] = f2bf(v);
          } else if (n < 1536) {
            const int n2 = n - 768, h = n2 >> 6, dh = n2 & 63;
            o1[(((size_t)(b * NH + h)) * SEQ + nq) * DHD + dh] = f2bf(v);
          } else {
            const int n2 = n - 1536, h = n2 >> 6, dh = n2 & 63;
            o2[(((size_t)(b * NH + h)) * DHD + dh) * SEQ + nq] = f2bf(v);  // V^T
          }
        } else if constexpr (MODE == MODE_PROJ) {
          const size_t off = (size_t)m * D_MODEL + n;
          outF[off] = v + resid[off];
        } else if constexpr (MODE == MODE_FFN1) {
          const float g3 = v * v * v;
          const float gl = 0.5f * v * (1.0f + tanhf(0.7978845608028654f * (v + 0.044715f * g3)));
          o0[(size_t)m * DFF + n] = f2bf(gl);
        } else {  // FFN2: in-place residual on outF (x2 lives there)
          const size_t off = (size_t)m * D_MODEL + n;
          outF[off] = v + resid[off];
        }
      }
    }
  }
}

// ------- fused flash attention: 4 waves x 32 q-rows, 32x32x16 MFMA ----------
// K/V staged into LDS in fragment order (shared by all 4 waves); swapped
// operands: S^T[k][q] = mfma(K,Q) so q = lane&31, k = reg-mapped; softmax
// fully in-lane with defer-max; P via wave-private LDS round-trip.
__global__ __launch_bounds__(256, 3)
void attn_kernel(const unsigned short* __restrict__ q, const unsigned short* __restrict__ k,
                 const unsigned short* __restrict__ vt, const unsigned short* __restrict__ bF,
                 unsigned short* __restrict__ ctx) {
  // kv slots: [buf][slot 0..15][64 lanes * 8 shorts]; slots 0-7 = K (kt*4+ds),
  // slots 8-15 = V (8 + dt*4 + kh). Each slot = one ds_read_b128 fragment set.
  __shared__ alignas(16) unsigned short kv[2][16][64 * 8];
  constexpr int PSTR = 76;  // shorts; 152B row: 2-way max bank aliasing (free)
  __shared__ alignas(16) unsigned short pbuf[4][32 * PSTR];
  const int tid = threadIdx.x, w = tid >> 6, lane = tid & 63;
  const int l31 = lane & 31, hi = lane >> 5;
  // XCD-chunked swizzle (768 % 8 == 0 -> bijective): 12 bh per XCD, K/V L2-res.
  const int bid = (blockIdx.x & 7) * 96 + (blockIdx.x >> 3);
  const int bh = bid >> 3, qblk = bid & 7;
  const int b = bh / NH, h = bh % NH;
  const int q0w = qblk * 128 + w * 32;
  const unsigned short* qp = q + (size_t)bh * SEQ * DHD;
  const unsigned short* kp = k + (size_t)bh * SEQ * DHD;
  const unsigned short* vp = vt + (size_t)bh * DHD * SEQ;
  // bias fragment stream for this wave's 32 q-rows (qt = qblk*4 + w)
  const unsigned short* bfp = bF + ((((size_t)(h * 32 + qblk * 4 + w)) * 32) * 64 + lane) * 16;

  // Q B-fragments (kept all kernel): col q = l31, d = ds*16 + hi*8 + e
  bf16x8 Qf[4];
#pragma unroll
  for (int ds = 0; ds < 4; ++ds)
    Qf[ds] = *(const bf16x8*)(qp + (size_t)(q0w + l31) * DHD + ds * 16 + hi * 8);

  f32x16 o[2];
#pragma unroll
  for (int dt = 0; dt < 2; ++dt) o[dt] = (f32x16)(0.f);
  float mrun = -INFINITY, lrun = 0.f;
  const float scale = 0.125f;  // 1/sqrt(64)
  unsigned short* pw = pbuf[w];

  auto stage = [&](int buf, int kb) {
    if (w < 2) {  // K slots: kt = w, ds 0..3; lane = A-frag row k, cols d
      const unsigned short* g0 = kp + (size_t)(kb * 64 + w * 32 + l31) * DHD + hi * 8;
#pragma unroll
      for (int ds = 0; ds < 4; ++ds)
        gload_lds16(g0 + ds * 16, &kv[buf][w * 4 + ds][0]);
    } else {      // V slots: dt = w-2, kh 0..3; lane = A-frag row d, cols k
      const int dt = w - 2;
      const unsigned short* g0 = vp + (size_t)(dt * 32 + l31) * SEQ + kb * 64 + hi * 8;
#pragma unroll
      for (int kh = 0; kh < 4; ++kh)
        gload_lds16(g0 + kh * 16, &kv[buf][8 + dt * 4 + kh][0]);
    }
  };

  stage(0, 0);
  __syncthreads();
  for (int kb = 0; kb < SEQ / 64; ++kb) {
    const int buf = kb & 1;
    if (kb + 1 < SEQ / 64) stage(buf ^ 1, kb + 1);

    // ---- S^T for 64 keys: 2 kt-tiles x 4 d-slices
    f32x16 s0 = (f32x16)(0.f), s1 = (f32x16)(0.f);
    __builtin_amdgcn_s_setprio(1);
#pragma unroll
    for (int ds = 0; ds < 4; ++ds) {
      bf16x8 kf0 = *(const bf16x8*)&kv[buf][ds][lane * 8];
      s0 = mfma32(kf0, Qf[ds], s0);
      bf16x8 kf1 = *(const bf16x8*)&kv[buf][4 + ds][lane * 8];
      s1 = mfma32(kf1, Qf[ds], s1);
    }
    __builtin_amdgcn_s_setprio(0);

    // ---- bias add (bf16 fragment stream, coalesced)
    const unsigned short* bb = bfp + (size_t)(kb * 2) * 64 * 16;
    uint4 a0 = *(const uint4*)(bb),            a1 = *(const uint4*)(bb + 8);
    uint4 c0 = *(const uint4*)(bb + 64 * 16),  c1 = *(const uint4*)(bb + 64 * 16 + 8);
    unsigned uw0[8] = {a0.x, a0.y, a0.z, a0.w, a1.x, a1.y, a1.z, a1.w};
    unsigned uw1[8] = {c0.x, c0.y, c0.z, c0.w, c1.x, c1.y, c1.z, c1.w};
    float p0[16], p1[16];
#pragma unroll
    for (int j = 0; j < 8; ++j) {
      p0[2 * j]     = fmaf(s0[2 * j],     scale, __uint_as_float(uw0[j] << 16));
      p0[2 * j + 1] = fmaf(s0[2 * j + 1], scale, __uint_as_float(uw0[j] & 0xffff0000u));
      p1[2 * j]     = fmaf(s1[2 * j],     scale, __uint_as_float(uw1[j] << 16));
      p1[2 * j + 1] = fmaf(s1[2 * j + 1], scale, __uint_as_float(uw1[j] & 0xffff0000u));
    }

    // ---- softmax (defer-max): in-lane max over 32, cross-pair only on rescale
    float pmax = p0[0];
#pragma unroll
    for (int i = 1; i < 16; ++i) pmax = fmaxf(pmax, p0[i]);
#pragma unroll
    for (int i = 0; i < 16; ++i) pmax = fmaxf(pmax, p1[i]);
    if (!__all(pmax - mrun <= 8.0f)) {
      float pm = fmaxf(pmax, __shfl_xor(pmax, 32));
      const float mn = fmaxf(mrun, pm);
      const float al = __expf(mrun - mn);
      mrun = mn;
      lrun *= al;
#pragma unroll
      for (int dt = 0; dt < 2; ++dt)
#pragma unroll
        for (int r = 0; r < 16; ++r) o[dt][r] *= al;
    }
#pragma unroll
    for (int i = 0; i < 16; ++i) { p0[i] = __expf(p0[i] - mrun); lrun += p0[i]; }
#pragma unroll
    for (int i = 0; i < 16; ++i) { p1[i] = __expf(p1[i] - mrun); lrun += p1[i]; }

    // ---- pack P -> bf16, write P^T[q][64] (wave-private), read B-frags
#pragma unroll
    for (int g = 0; g < 4; ++g) {
      uint2 w0, w1;
      asm("v_cvt_pk_bf16_f32 %0, %1, %2" : "=v"(w0.x) : "v"(p0[4 * g]),     "v"(p0[4 * g + 1]));
      asm("v_cvt_pk_bf16_f32 %0, %1, %2" : "=v"(w0.y) : "v"(p0[4 * g + 2]), "v"(p0[4 * g + 3]));
      asm("v_cvt_pk_bf16_f32 %0, %1, %2" : "=v"(w1.x) : "v"(p1[4 * g]),     "v"(p1[4 * g + 1]));
      asm("v_cvt_pk_bf16_f32 %0, %1, %2" : "=v"(w1.y) : "v"(p1[4 * g + 2]), "v"(p1[4 * g + 3]));
      // quad g of kt-tile covers k = kt*32 + g*8 + 4*hi + {0..3}
      *(uint2*)(pw + l31 * PSTR +      g * 8 + 4 * hi) = w0;
      *(uint2*)(pw + l31 * PSTR + 32 + g * 8 + 4 * hi) = w1;
    }
    bf16x8 pf[4];
#pragma unroll
    for (int kh = 0; kh < 4; ++kh)
      pf[kh] = *(const bf16x8*)(pw + l31 * PSTR + kh * 16 + hi * 8);

    // ---- PV: O^T[d][q] += V^T-frag x P-frag
    __builtin_amdgcn_s_setprio(1);
#pragma unroll
    for (int dt = 0; dt < 2; ++dt)
#pragma unroll
      for (int kh = 0; kh < 4; ++kh) {
        bf16x8 vf = *(const bf16x8*)&kv[buf][8 + dt * 4 + kh][lane * 8];
        o[dt] = mfma32(vf, pf[kh], o[dt]);
      }
    __builtin_amdgcn_s_setprio(0);

    __syncthreads();  // staging of buf^1 complete + all waves done with buf
  }

  lrun += __shfl_xor(lrun, 32);
  const float inv = 1.0f / lrun;
  // O^T reg r: d = dt*32 + (r&3) + 8*(r>>2) + 4*hi, q = l31
  unsigned short* crow = ctx + ((size_t)b * SEQ + q0w + l31) * D_MODEL + h * DHD;
#pragma unroll
  for (int dt = 0; dt < 2; ++dt)
#pragma unroll
    for (int g = 0; g < 4; ++g) {
      us4 ov;
#pragma unroll
      for (int j = 0; j < 4; ++j) ov[j] = f2bf(o[dt][4 * g + j] * inv);
      *(us4*)(crow + dt * 32 + g * 8 + 4 * hi) = ov;
    }
}

// ----------------------------------------------------------------------------
extern "C" void kernel_launch(void* const* d_in, const int* in_sizes, int n_in,
                              void* d_out, int out_size, void* d_ws, size_t ws_size,
                              hipStream_t stream) {
  (void)in_sizes; (void)n_in; (void)out_size; (void)ws_size;
  const float* x     = (const float*)d_in[0];
  const float* ln1_g = (const float*)d_in[1];
  const float* ln1_b = (const float*)d_in[2];
  const float* wqkv  = (const float*)d_in[3];
  const float* bqkv  = (const float*)d_in[4];
  const float* wo    = (const float*)d_in[5];
  const float* bo    = (const float*)d_in[6];
  const float* rel   = (const float*)d_in[7];
  const float* ln2_g = (const float*)d_in[8];
  const float* ln2_b = (const float*)d_in[9];
  const float* w1    = (const float*)d_in[10];
  const float* b1    = (const float*)d_in[11];
  const float* w2    = (const float*)d_in[12];
  const float* b2    = (const float*)d_in[13];
  float* out = (float*)d_out;

  char* p = (char*)d_ws;
  auto take = [&](size_t bytes) {
    void* r = (void*)p;
    p += (bytes + 255) & ~(size_t)255;
    return r;
  };
  unsigned short* hbuf  = (unsigned short*)take((size_t)NTOK * D_MODEL * 2);
  unsigned short* wqkvT = (unsigned short*)take((size_t)2304 * 768 * 2);
  unsigned short* woT   = (unsigned short*)take((size_t)768 * 768 * 2);
  unsigned short* w1T   = (unsigned short*)take((size_t)3072 * 768 * 2);
  unsigned short* w2T   = (unsigned short*)take((size_t)768 * 3072 * 2);
  unsigned short* qbuf  = (unsigned short*)take((size_t)8 * NH * SEQ * DHD * 2);
  unsigned short* kbuf  = (unsigned short*)take((size_t)8 * NH * SEQ * DHD * 2);
  unsigned short* vtbuf = (unsigned short*)take((size_t)8 * NH * SEQ * DHD * 2);
  unsigned short* ctxb  = (unsigned short*)take((size_t)NTOK * D_MODEL * 2);
  unsigned short* h1buf = (unsigned short*)take((size_t)NTOK * DFF * 2);
  // biasF (25.2 MB) aliases h1buf (50.3 MB): dead before FFN1 writes h1buf.
  unsigned short* biasF = h1buf;
  // x2 (post-attention residual stream) lives in d_out (fp32).

  // weight prep (independent of activations)
  wtrans_kernel<<<dim3(2304 / 32, 768 / 32), 256, 0, stream>>>(wqkv, wqkvT, 768, 2304);
  wtrans_kernel<<<dim3(768 / 32, 768 / 32), 256, 0, stream>>>(wo, woT, 768, 768);
  wtrans_kernel<<<dim3(3072 / 32, 768 / 32), 256, 0, stream>>>(w1, w1T, 768, 3072);
  wtrans_kernel<<<dim3(768 / 32, 3072 / 32), 256, 0, stream>>>(w2, w2T, 3072, 768);
  // bias -> bf16 fragment order
  brelayout_kernel<<<NH * 32 * 32 / 4, 256, 0, stream>>>(rel, biasF);

  // LN1: x -> h (bf16)
  ln_kernel<<<NTOK / 4, 256, 0, stream>>>(x, ln1_g, ln1_b, hbuf);
  // QKV: h @ wqkv + bqkv -> q,k,Vt (bf16, attention layouts)
  gemm_bt<MODE_QKV><<<dim3(2304 / 128, NTOK / 128), 256, 0, stream>>>(
      hbuf, wqkvT, 768, bqkv, nullptr, nullptr, qbuf, kbuf, vtbuf);
  // attention -> ctx (bf16, [tok][D])
  attn_kernel<<<8 * NH * (SEQ / 128), 256, 0, stream>>>(qbuf, kbuf, vtbuf, biasF, ctxb);
  // proj: ctx @ wo + bo + x -> x2 (fp32, in d_out)
  gemm_bt<MODE_PROJ><<<dim3(768 / 128, NTOK / 128), 256, 0, stream>>>(
      ctxb, woT, 768, bo, x, out, nullptr, nullptr, nullptr);
  // LN2: x2 -> h2 (bf16, reuse hbuf)
  ln_kernel<<<NTOK / 4, 256, 0, stream>>>(out, ln2_g, ln2_b, hbuf);
  // FFN1: h2 @ w1 + b1, gelu -> h1 (bf16)
  gemm_bt<MODE_FFN1><<<dim3(DFF / 128, NTOK / 128), 256, 0, stream>>>(
      hbuf, w1T, 768, b1, nullptr, nullptr, h1buf, nullptr, nullptr);
  // FFN2: h1 @ w2 + b2 + x2 -> out (fp32, in place on d_out)
  gemm_bt<MODE_FFN2><<<dim3(768 / 128, NTOK / 128), 256, 0, stream>>>(
      h1buf, w2T, 3072, b2, out, out, nullptr, nullptr, nullptr);
}

// Round 6
// 284.416 us; speedup vs baseline: 1.6702x; 1.1293x over previous
//
#include <hip/hip_runtime.h>
#include <hip/hip_bf16.h>
#include <math.h>

#define D_MODEL 768
#define NTOK    8192   // B*N
#define SEQ     1024
#define NH      12
#define DHD     64
#define DFF     3072

typedef __attribute__((ext_vector_type(8)))  __bf16 bf16x8;
typedef __attribute__((ext_vector_type(4)))  float  f32x4;
typedef __attribute__((ext_vector_type(16))) float  f32x16;
typedef __attribute__((ext_vector_type(4)))  unsigned short us4;

typedef const __attribute__((address_space(1))) void g_void;
typedef __attribute__((address_space(3))) void lds_void;

__device__ __forceinline__ unsigned short f2bf(float f) {
  unsigned u = __float_as_uint(f);
  u += 0x7fffu + ((u >> 16) & 1u);   // RNE to bf16
  return (unsigned short)(u >> 16);
}

__device__ __forceinline__ f32x4 mfma16(bf16x8 a, bf16x8 b, f32x4 c) {
  return __builtin_amdgcn_mfma_f32_16x16x32_bf16(a, b, c, 0, 0, 0);
}
__device__ __forceinline__ f32x16 mfma32(bf16x8 a, bf16x8 b, f32x16 c) {
  return __builtin_amdgcn_mfma_f32_32x32x16_bf16(a, b, c, 0, 0, 0);
}

// async global->LDS, 16B per lane; LDS dest = uniform base + lane*16
__device__ __forceinline__ void gload_lds16(const unsigned short* g, unsigned short* l) {
  __builtin_amdgcn_global_load_lds((g_void*)g, (lds_void*)l, 16, 0, 0);
}

// ---------------- LayerNorm: one wave per row of 768, fp32 in -> bf16 out ----
__global__ __launch_bounds__(256)
void ln_kernel(const float* __restrict__ x, const float* __restrict__ gam,
               const float* __restrict__ bet, unsigned short* __restrict__ out) {
  const int w = threadIdx.x >> 6, lane = threadIdx.x & 63;
  const size_t row = (size_t)blockIdx.x * 4 + w;
  const float* xr = x + row * D_MODEL;
  f32x4 v[3];
#pragma unroll
  for (int c = 0; c < 3; ++c) v[c] = *(const f32x4*)(xr + c * 256 + lane * 4);
  float s = 0.f;
#pragma unroll
  for (int c = 0; c < 3; ++c)
#pragma unroll
    for (int j = 0; j < 4; ++j) s += v[c][j];
#pragma unroll
  for (int o = 32; o; o >>= 1) s += __shfl_xor(s, o);
  const float mu = s * (1.0f / D_MODEL);
  float vs = 0.f;
#pragma unroll
  for (int c = 0; c < 3; ++c)
#pragma unroll
    for (int j = 0; j < 4; ++j) { float d = v[c][j] - mu; vs += d * d; }
#pragma unroll
  for (int o = 32; o; o >>= 1) vs += __shfl_xor(vs, o);
  const float rs = rsqrtf(vs * (1.0f / D_MODEL) + 1e-5f);
  unsigned short* orow = out + row * D_MODEL;
#pragma unroll
  for (int c = 0; c < 3; ++c) {
    us4 o4;
#pragma unroll
    for (int j = 0; j < 4; ++j) {
      int idx = c * 256 + lane * 4 + j;
      o4[j] = f2bf((v[c][j] - mu) * rs * gam[idx] + bet[idx]);
    }
    *(us4*)(orow + c * 256 + lane * 4) = o4;
  }
}

// ------------- weight transpose + cast: W[K][Nc] f32 -> Wt[Nc][K] bf16 -------
__global__ __launch_bounds__(256)
void wtrans_kernel(const float* __restrict__ W, unsigned short* __restrict__ Wt,
                   int K, int Nc) {
  __shared__ float t[32][33];
  const int tx = threadIdx.x & 31, ty = threadIdx.x >> 5;  // 32x8
  const int nb = blockIdx.x * 32, kb = blockIdx.y * 32;
#pragma unroll
  for (int i = 0; i < 4; ++i)
    t[ty + 8 * i][tx] = W[(size_t)(kb + ty + 8 * i) * Nc + nb + tx];
  __syncthreads();
#pragma unroll
  for (int i = 0; i < 4; ++i)
    Wt[(size_t)(nb + ty + 8 * i) * K + kb + tx] = f2bf(t[tx][ty + 8 * i]);
}

// ------ bias reshape: rel[H][N][N] f32 -> biasF[h][qt32][kt32][lane][16] bf16
// Fragment order of the 32x32 S^T tile: lane l covers q = qt*32+(l&31);
// reg r covers k = kt*32 + (r&3) + 8*(r>>2) + 4*(l>>5). Packed (r0,r1)(r2,r3)..
__global__ __launch_bounds__(256)
void brelayout_kernel(const float* __restrict__ rel, unsigned short* __restrict__ bF) {
  const int gw = blockIdx.x * 4 + (threadIdx.x >> 6);  // (h*32+qt)*32+ktg
  const int lane = threadIdx.x & 63;
  const int ktg = gw & 31, qt = (gw >> 5) & 31, h = gw >> 10;
  const int q = qt * 32 + (lane & 31), hi = lane >> 5;
  const float* src = rel + ((size_t)h * SEQ + q) * SEQ + ktg * 32 + 4 * hi;
  unsigned ow[8];
#pragma unroll
  for (int g = 0; g < 4; ++g) {
    f32x4 v = *(const f32x4*)(src + g * 8);
    asm("v_cvt_pk_bf16_f32 %0, %1, %2" : "=v"(ow[2 * g])     : "v"(v[0]), "v"(v[1]));
    asm("v_cvt_pk_bf16_f32 %0, %1, %2" : "=v"(ow[2 * g + 1]) : "v"(v[2]), "v"(v[3]));
  }
  unsigned short* dst = bF + (((size_t)gw) * 64 + lane) * 16;
  *(uint4*)(dst)     = make_uint4(ow[0], ow[1], ow[2], ow[3]);
  *(uint4*)(dst + 8) = make_uint4(ow[4], ow[5], ow[6], ow[7]);
}

// -------- GEMM: C[M][N] = A[M][K] @ Bt[N][K]^T, bf16, fused epilogue --------
// 128x128 tile, BK=64, 4 waves (wave tile 64x64 = 2x2 of 32x32x16 MFMA).
// LDS XOR-swizzle on the per-lane GLOBAL source (gload dest linear) + ds_read.
#define MODE_QKV  0
#define MODE_PROJ 1
#define MODE_FFN1 2
#define MODE_FFN2 3

template <int MODE>
__global__ __launch_bounds__(256)
void gemm_bt(const unsigned short* __restrict__ A, const unsigned short* __restrict__ Bt,
             int K, const float* __restrict__ bias, const float* __restrict__ resid,
             float* __restrict__ outF, unsigned short* __restrict__ o0,
             unsigned short* __restrict__ o1, unsigned short* __restrict__ o2) {
  __shared__ alignas(16) unsigned short smem[2][2][128 * 64];  // [A/B][buf][tile]
  const int tid = threadIdx.x;
  const int w = tid >> 6, lane = tid & 63;
  const int l31 = lane & 31, hi = lane >> 5;
  const int wm = w >> 1, wn = w & 1;
  // XCD-chunked bijective swizzle (all grids are multiples of 8 blocks)
  const int nwg = gridDim.x * gridDim.y;
  const int bid0 = blockIdx.y * gridDim.x + blockIdx.x;
  const int cpx = nwg >> 3;
  const int bid = (bid0 & 7) * cpx + (bid0 >> 3);
  const int bx = bid % gridDim.x, by = bid / gridDim.x;
  const size_t m0 = (size_t)by * 128;
  const size_t n0 = (size_t)bx * 128;
  const unsigned short* gA = A + m0 * K;
  const unsigned short* gB = Bt + n0 * K;

  // staging decomposition: lane -> (row-in-8-group, 16B unit), source col XOR'd
  const int r8 = lane >> 3;         // 0..7
  const int u8 = lane & 7;          // 16B unit 0..7 within 128B row
  const int ucol = (u8 ^ r8) * 8;   // swizzled element offset within BK=64 row

  f32x16 acc[2][2];
#pragma unroll
  for (int i = 0; i < 2; ++i)
#pragma unroll
    for (int j = 0; j < 2; ++j) acc[i][j] = (f32x16)(0.f);
  const int nk = K >> 6;

  auto stage = [&](int buf, int kt) {
#pragma unroll
    for (int g = 0; g < 4; ++g) {
      const int rowb = w * 32 + g * 8;  // wave-uniform base row (multiple of 8)
      gload_lds16(gA + (size_t)(rowb + r8) * K + kt * 64 + ucol, &smem[0][buf][rowb * 64]);
      gload_lds16(gB + (size_t)(rowb + r8) * K + kt * 64 + ucol, &smem[1][buf][rowb * 64]);
    }
  };

  // frag read offsets: row = base + l31 (base % 8 == 0), unit j = ks*2 + hi
  const int swr = l31 & 7;
  const int rA = (wm * 64 + l31) * 64;
  const int rB = (wn * 64 + l31) * 64;

  stage(0, 0);
  __syncthreads();
  for (int kt = 0; kt < nk; ++kt) {
    const int buf = kt & 1;
    if (kt + 1 < nk) stage(buf ^ 1, kt + 1);
    bf16x8 af[2][4], bf[2][4];
#pragma unroll
    for (int mt = 0; mt < 2; ++mt)
#pragma unroll
      for (int ks = 0; ks < 4; ++ks) {
        af[mt][ks] = *(const bf16x8*)&smem[0][buf][rA + mt * 2048 + (((ks * 2 + hi) ^ swr) * 8)];
        bf[mt][ks] = *(const bf16x8*)&smem[1][buf][rB + mt * 2048 + (((ks * 2 + hi) ^ swr) * 8)];
      }
#pragma unroll
    for (int mt = 0; mt < 2; ++mt)
#pragma unroll
      for (int nt = 0; nt < 2; ++nt)
#pragma unroll
        for (int ks = 0; ks < 4; ++ks)
          acc[mt][nt] = mfma32(af[mt][ks], bf[nt][ks], acc[mt][nt]);
    __syncthreads();   // staging of buf^1 complete + all waves done reading buf
  }

  // ---- V-region of QKV: transpose through (now dead) LDS, coalesced stores
  if constexpr (MODE == MODE_QKV) {
    if (bx >= 12) {
      unsigned short* tb = &smem[0][0][0];  // [128 n][136 m] (pad: 16B rows, banks ok)
#pragma unroll
      for (int mt = 0; mt < 2; ++mt)
#pragma unroll
        for (int nt = 0; nt < 2; ++nt)
#pragma unroll
          for (int r = 0; r < 16; ++r) {
            const int nl = wn * 64 + nt * 32 + l31;
            const int ml = wm * 64 + mt * 32 + (r & 3) + 8 * (r >> 2) + 4 * hi;
            tb[nl * 136 + ml] = f2bf(acc[mt][nt][r] + bias[(int)n0 + nl]);
          }
      __syncthreads();
      const int rr = tid & 127, half = tid >> 7;
      const int n2 = ((int)n0 - 1536) + rr;
      const int hh = n2 >> 6, dh = n2 & 63;
      const int b2 = (int)(m0 >> 10), nq0 = (int)(m0 & 1023);
      unsigned short* dst = o2 + ((size_t)(b2 * NH + hh) * DHD + dh) * SEQ + nq0 + half * 64;
      const unsigned short* src = tb + rr * 136 + half * 64;
#pragma unroll
      for (int i = 0; i < 4; ++i)
        *(uint4*)(dst + i * 8) = *(const uint4*)(src + i * 8);
      return;
    }
  }

  // epilogue: 32x32 C/D map: n = tile + l31, m = tile + (r&3) + 8*(r>>2) + 4*hi
#pragma unroll
  for (int mt = 0; mt < 2; ++mt) {
#pragma unroll
    for (int nt = 0; nt < 2; ++nt) {
#pragma unroll
      for (int r = 0; r < 16; ++r) {
        const int m = (int)m0 + wm * 64 + mt * 32 + (r & 3) + 8 * (r >> 2) + 4 * hi;
        const int n = (int)n0 + wn * 64 + nt * 32 + l31;
        float v = acc[mt][nt][r] + bias[n];
        if constexpr (MODE == MODE_QKV) {
          const int b = m >> 10, nq = m & 1023;
          if (n < 768) {
            const int h = n >> 6, dh = n & 63;
            o0[(((size_t)(b * NH + h)) * SEQ + nq) * DHD + dh] = f2bf(v);
          } else {
            const int n2 = n - 768, h = n2 >> 6, dh = n2 & 63;
            o1[(((size_t)(b * NH + h)) * SEQ + nq) * DHD + dh] = f2bf(v);
          }
        } else if constexpr (MODE == MODE_PROJ) {
          const size_t off = (size_t)m * D_MODEL + n;
          outF[off] = v + resid[off];
        } else if constexpr (MODE == MODE_FFN1) {
          // gelu(v) = 0.5v(1+tanh(u)) == v * sigmoid(2u), u=0.79788456(v+0.044715v^3)
          const float e = __expf(-1.5957691216057308f * (v + 0.044715f * v * v * v));
          o0[(size_t)m * DFF + n] = f2bf(v / (1.0f + e));
        } else {  // FFN2: in-place residual on outF (x2 lives there)
          const size_t off = (size_t)m * D_MODEL + n;
          outF[off] = v + resid[off];
        }
      }
    }
  }
}

// ------- fused flash attention: 4 waves x 32 q-rows, 32x32x16 MFMA ----------
// K/V staged into LDS in fragment order (shared by all 4 waves); swapped
// operands: S^T[k][q] = mfma(K,Q) so q = lane&31, k = reg-mapped; softmax
// fully in-lane with defer-max; P via wave-private LDS round-trip.
__global__ __launch_bounds__(256, 3)
void attn_kernel(const unsigned short* __restrict__ q, const unsigned short* __restrict__ k,
                 const unsigned short* __restrict__ vt, const unsigned short* __restrict__ bF,
                 unsigned short* __restrict__ ctx) {
  // kv slots: [buf][slot 0..15][64 lanes * 8 shorts]; slots 0-7 = K (kt*4+ds),
  // slots 8-15 = V (8 + dt*4 + kh). Each slot = one ds_read_b128 fragment set.
  __shared__ alignas(16) unsigned short kv[2][16][64 * 8];
  constexpr int PSTR = 76;  // shorts; 152B row: 2-way max bank aliasing (free)
  __shared__ alignas(16) unsigned short pbuf[4][32 * PSTR];
  const int tid = threadIdx.x, w = tid >> 6, lane = tid & 63;
  const int l31 = lane & 31, hi = lane >> 5;
  // XCD-chunked swizzle (768 % 8 == 0 -> bijective): 12 bh per XCD, K/V L2-res.
  const int bid = (blockIdx.x & 7) * 96 + (blockIdx.x >> 3);
  const int bh = bid >> 3, qblk = bid & 7;
  const int b = bh / NH, h = bh % NH;
  const int q0w = qblk * 128 + w * 32;
  const unsigned short* qp = q + (size_t)bh * SEQ * DHD;
  const unsigned short* kp = k + (size_t)bh * SEQ * DHD;
  const unsigned short* vp = vt + (size_t)bh * DHD * SEQ;
  // bias fragment stream for this wave's 32 q-rows (qt = qblk*4 + w)
  const unsigned short* bfp = bF + ((((size_t)(h * 32 + qblk * 4 + w)) * 32) * 64 + lane) * 16;

  // Q B-fragments (kept all kernel): col q = l31, d = ds*16 + hi*8 + e
  bf16x8 Qf[4];
#pragma unroll
  for (int ds = 0; ds < 4; ++ds)
    Qf[ds] = *(const bf16x8*)(qp + (size_t)(q0w + l31) * DHD + ds * 16 + hi * 8);

  f32x16 o[2];
#pragma unroll
  for (int dt = 0; dt < 2; ++dt) o[dt] = (f32x16)(0.f);
  float mrun = -INFINITY, lrun = 0.f;
  const float scale = 0.125f;  // 1/sqrt(64)
  unsigned short* pw = pbuf[w];

  auto stage = [&](int buf, int kb) {
    if (w < 2) {  // K slots: kt = w, ds 0..3; lane = A-frag row k, cols d
      const unsigned short* g0 = kp + (size_t)(kb * 64 + w * 32 + l31) * DHD + hi * 8;
#pragma unroll
      for (int ds = 0; ds < 4; ++ds)
        gload_lds16(g0 + ds * 16, &kv[buf][w * 4 + ds][0]);
    } else {      // V slots: dt = w-2, kh 0..3; lane = A-frag row d, cols k
      const int dt = w - 2;
      const unsigned short* g0 = vp + (size_t)(dt * 32 + l31) * SEQ + kb * 64 + hi * 8;
#pragma unroll
      for (int kh = 0; kh < 4; ++kh)
        gload_lds16(g0 + kh * 16, &kv[buf][8 + dt * 4 + kh][0]);
    }
  };

  stage(0, 0);
  __syncthreads();
  for (int kb = 0; kb < SEQ / 64; ++kb) {
    const int buf = kb & 1;
    if (kb + 1 < SEQ / 64) stage(buf ^ 1, kb + 1);

    // ---- S^T for 64 keys: 2 kt-tiles x 4 d-slices
    f32x16 s0 = (f32x16)(0.f), s1 = (f32x16)(0.f);
    __builtin_amdgcn_s_setprio(1);
#pragma unroll
    for (int ds = 0; ds < 4; ++ds) {
      bf16x8 kf0 = *(const bf16x8*)&kv[buf][ds][lane * 8];
      s0 = mfma32(kf0, Qf[ds], s0);
      bf16x8 kf1 = *(const bf16x8*)&kv[buf][4 + ds][lane * 8];
      s1 = mfma32(kf1, Qf[ds], s1);
    }
    __builtin_amdgcn_s_setprio(0);

    // ---- bias add (bf16 fragment stream, coalesced)
    const unsigned short* bb = bfp + (size_t)(kb * 2) * 64 * 16;
    uint4 a0 = *(const uint4*)(bb),            a1 = *(const uint4*)(bb + 8);
    uint4 c0 = *(const uint4*)(bb + 64 * 16),  c1 = *(const uint4*)(bb + 64 * 16 + 8);
    unsigned uw0[8] = {a0.x, a0.y, a0.z, a0.w, a1.x, a1.y, a1.z, a1.w};
    unsigned uw1[8] = {c0.x, c0.y, c0.z, c0.w, c1.x, c1.y, c1.z, c1.w};
    float p0[16], p1[16];
#pragma unroll
    for (int j = 0; j < 8; ++j) {
      p0[2 * j]     = fmaf(s0[2 * j],     scale, __uint_as_float(uw0[j] << 16));
      p0[2 * j + 1] = fmaf(s0[2 * j + 1], scale, __uint_as_float(uw0[j] & 0xffff0000u));
      p1[2 * j]     = fmaf(s1[2 * j],     scale, __uint_as_float(uw1[j] << 16));
      p1[2 * j + 1] = fmaf(s1[2 * j + 1], scale, __uint_as_float(uw1[j] & 0xffff0000u));
    }

    // ---- softmax (defer-max): in-lane max over 32, cross-pair only on rescale
    float pmax = p0[0];
#pragma unroll
    for (int i = 1; i < 16; ++i) pmax = fmaxf(pmax, p0[i]);
#pragma unroll
    for (int i = 0; i < 16; ++i) pmax = fmaxf(pmax, p1[i]);
    if (!__all(pmax - mrun <= 8.0f)) {
      float pm = fmaxf(pmax, __shfl_xor(pmax, 32));
      const float mn = fmaxf(mrun, pm);
      const float al = __expf(mrun - mn);
      mrun = mn;
      lrun *= al;
#pragma unroll
      for (int dt = 0; dt < 2; ++dt)
#pragma unroll
        for (int r = 0; r < 16; ++r) o[dt][r] *= al;
    }
#pragma unroll
    for (int i = 0; i < 16; ++i) { p0[i] = __expf(p0[i] - mrun); lrun += p0[i]; }
#pragma unroll
    for (int i = 0; i < 16; ++i) { p1[i] = __expf(p1[i] - mrun); lrun += p1[i]; }

    // ---- pack P -> bf16, write P^T[q][64] (wave-private), read B-frags
#pragma unroll
    for (int g = 0; g < 4; ++g) {
      uint2 w0, w1;
      asm("v_cvt_pk_bf16_f32 %0, %1, %2" : "=v"(w0.x) : "v"(p0[4 * g]),     "v"(p0[4 * g + 1]));
      asm("v_cvt_pk_bf16_f32 %0, %1, %2" : "=v"(w0.y) : "v"(p0[4 * g + 2]), "v"(p0[4 * g + 3]));
      asm("v_cvt_pk_bf16_f32 %0, %1, %2" : "=v"(w1.x) : "v"(p1[4 * g]),     "v"(p1[4 * g + 1]));
      asm("v_cvt_pk_bf16_f32 %0, %1, %2" : "=v"(w1.y) : "v"(p1[4 * g + 2]), "v"(p1[4 * g + 3]));
      // quad g of kt-tile covers k = kt*32 + g*8 + 4*hi + {0..3}
      *(uint2*)(pw + l31 * PSTR +      g * 8 + 4 * hi) = w0;
      *(uint2*)(pw + l31 * PSTR + 32 + g * 8 + 4 * hi) = w1;
    }
    bf16x8 pf[4];
#pragma unroll
    for (int kh = 0; kh < 4; ++kh)
      pf[kh] = *(const bf16x8*)(pw + l31 * PSTR + kh * 16 + hi * 8);

    // ---- PV: O^T[d][q] += V^T-frag x P-frag
    __builtin_amdgcn_s_setprio(1);
#pragma unroll
    for (int dt = 0; dt < 2; ++dt)
#pragma unroll
      for (int kh = 0; kh < 4; ++kh) {
        bf16x8 vf = *(const bf16x8*)&kv[buf][8 + dt * 4 + kh][lane * 8];
        o[dt] = mfma32(vf, pf[kh], o[dt]);
      }
    __builtin_amdgcn_s_setprio(0);

    __syncthreads();  // staging of buf^1 complete + all waves done with buf
  }

  lrun += __shfl_xor(lrun, 32);
  const float inv = 1.0f / lrun;
  // O^T reg r: d = dt*32 + (r&3) + 8*(r>>2) + 4*hi, q = l31
  unsigned short* crow = ctx + ((size_t)b * SEQ + q0w + l31) * D_MODEL + h * DHD;
#pragma unroll
  for (int dt = 0; dt < 2; ++dt)
#pragma unroll
    for (int g = 0; g < 4; ++g) {
      us4 ov;
#pragma unroll
      for (int j = 0; j < 4; ++j) ov[j] = f2bf(o[dt][4 * g + j] * inv);
      *(us4*)(crow + dt * 32 + g * 8 + 4 * hi) = ov;
    }
}

// ----------------------------------------------------------------------------
extern "C" void kernel_launch(void* const* d_in, const int* in_sizes, int n_in,
                              void* d_out, int out_size, void* d_ws, size_t ws_size,
                              hipStream_t stream) {
  (void)in_sizes; (void)n_in; (void)out_size; (void)ws_size;
  const float* x     = (const float*)d_in[0];
  const float* ln1_g = (const float*)d_in[1];
  const float* ln1_b = (const float*)d_in[2];
  const float* wqkv  = (const float*)d_in[3];
  const float* bqkv  = (const float*)d_in[4];
  const float* wo    = (const float*)d_in[5];
  const float* bo    = (const float*)d_in[6];
  const float* rel   = (const float*)d_in[7];
  const float* ln2_g = (const float*)d_in[8];
  const float* ln2_b = (const float*)d_in[9];
  const float* w1    = (const float*)d_in[10];
  const float* b1    = (const float*)d_in[11];
  const float* w2    = (const float*)d_in[12];
  const float* b2    = (const float*)d_in[13];
  float* out = (float*)d_out;

  char* p = (char*)d_ws;
  auto take = [&](size_t bytes) {
    void* r = (void*)p;
    p += (bytes + 255) & ~(size_t)255;
    return r;
  };
  unsigned short* hbuf  = (unsigned short*)take((size_t)NTOK * D_MODEL * 2);
  unsigned short* wqkvT = (unsigned short*)take((size_t)2304 * 768 * 2);
  unsigned short* woT   = (unsigned short*)take((size_t)768 * 768 * 2);
  unsigned short* w1T   = (unsigned short*)take((size_t)3072 * 768 * 2);
  unsigned short* w2T   = (unsigned short*)take((size_t)768 * 3072 * 2);
  unsigned short* qbuf  = (unsigned short*)take((size_t)8 * NH * SEQ * DHD * 2);
  unsigned short* kbuf  = (unsigned short*)take((size_t)8 * NH * SEQ * DHD * 2);
  unsigned short* vtbuf = (unsigned short*)take((size_t)8 * NH * SEQ * DHD * 2);
  unsigned short* ctxb  = (unsigned short*)take((size_t)NTOK * D_MODEL * 2);
  unsigned short* h1buf = (unsigned short*)take((size_t)NTOK * DFF * 2);
  // biasF (25.2 MB) aliases h1buf (50.3 MB): dead before FFN1 writes h1buf.
  unsigned short* biasF = h1buf;
  // x2 (post-attention residual stream) lives in d_out (fp32).

  // weight prep (independent of activations)
  wtrans_kernel<<<dim3(2304 / 32, 768 / 32), 256, 0, stream>>>(wqkv, wqkvT, 768, 2304);
  wtrans_kernel<<<dim3(768 / 32, 768 / 32), 256, 0, stream>>>(wo, woT, 768, 768);
  wtrans_kernel<<<dim3(3072 / 32, 768 / 32), 256, 0, stream>>>(w1, w1T, 768, 3072);
  wtrans_kernel<<<dim3(768 / 32, 3072 / 32), 256, 0, stream>>>(w2, w2T, 3072, 768);
  // bias -> bf16 fragment order
  brelayout_kernel<<<NH * 32 * 32 / 4, 256, 0, stream>>>(rel, biasF);

  // LN1: x -> h (bf16)
  ln_kernel<<<NTOK / 4, 256, 0, stream>>>(x, ln1_g, ln1_b, hbuf);
  // QKV: h @ wqkv + bqkv -> q,k,Vt (bf16, attention layouts)
  gemm_bt<MODE_QKV><<<dim3(2304 / 128, NTOK / 128), 256, 0, stream>>>(
      hbuf, wqkvT, 768, bqkv, nullptr, nullptr, qbuf, kbuf, vtbuf);
  // attention -> ctx (bf16, [tok][D])
  attn_kernel<<<8 * NH * (SEQ / 128), 256, 0, stream>>>(qbuf, kbuf, vtbuf, biasF, ctxb);
  // proj: ctx @ wo + bo + x -> x2 (fp32, in d_out)
  gemm_bt<MODE_PROJ><<<dim3(768 / 128, NTOK / 128), 256, 0, stream>>>(
      ctxb, woT, 768, bo, x, out, nullptr, nullptr, nullptr);
  // LN2: x2 -> h2 (bf16, reuse hbuf)
  ln_kernel<<<NTOK / 4, 256, 0, stream>>>(out, ln2_g, ln2_b, hbuf);
  // FFN1: h2 @ w1 + b1, gelu -> h1 (bf16)
  gemm_bt<MODE_FFN1><<<dim3(DFF / 128, NTOK / 128), 256, 0, stream>>>(
      hbuf, w1T, 768, b1, nullptr, nullptr, h1buf, nullptr, nullptr);
  // FFN2: h1 @ w2 + b2 + x2 -> out (fp32, in place on d_out)
  gemm_bt<MODE_FFN2><<<dim3(768 / 128, NTOK / 128), 256, 0, stream>>>(
      h1buf, w2T, 3072, b2, out, out, nullptr, nullptr, nullptr);
}

// Round 7
// 274.848 us; speedup vs baseline: 1.7283x; 1.0348x over previous
//
#include <hip/hip_runtime.h>
#include <hip/hip_bf16.h>
#include <math.h>

#define D_MODEL 768
#define NTOK    8192   // B*N
#define SEQ     1024
#define NH      12
#define DHD     64
#define DFF     3072

typedef __attribute__((ext_vector_type(8)))  __bf16 bf16x8;
typedef __attribute__((ext_vector_type(4)))  float  f32x4;
typedef __attribute__((ext_vector_type(16))) float  f32x16;
typedef __attribute__((ext_vector_type(4)))  unsigned short us4;

typedef const __attribute__((address_space(1))) void g_void;
typedef __attribute__((address_space(3))) void lds_void;

__device__ __forceinline__ unsigned short f2bf(float f) {
  unsigned u = __float_as_uint(f);
  u += 0x7fffu + ((u >> 16) & 1u);   // RNE to bf16
  return (unsigned short)(u >> 16);
}

__device__ __forceinline__ f32x4 mfma16(bf16x8 a, bf16x8 b, f32x4 c) {
  return __builtin_amdgcn_mfma_f32_16x16x32_bf16(a, b, c, 0, 0, 0);
}
__device__ __forceinline__ f32x16 mfma32(bf16x8 a, bf16x8 b, f32x16 c) {
  return __builtin_amdgcn_mfma_f32_32x32x16_bf16(a, b, c, 0, 0, 0);
}

// async global->LDS, 16B per lane; LDS dest = uniform base + lane*16
__device__ __forceinline__ void gload_lds16(const unsigned short* g, unsigned short* l) {
  __builtin_amdgcn_global_load_lds((g_void*)g, (lds_void*)l, 16, 0, 0);
}

// v_permlane32_swap_b32: a[32..63] <-> b[0..31] (both operands updated)
__device__ __forceinline__ void plswap(unsigned &a, unsigned &b) {
  asm("v_permlane32_swap_b32 %0, %1" : "+v"(a), "+v"(b));
}
__device__ __forceinline__ bf16x8 mk8(unsigned a, unsigned b, unsigned c, unsigned d) {
  union { unsigned u[4]; bf16x8 v; } t;
  t.u[0] = a; t.u[1] = b; t.u[2] = c; t.u[3] = d;
  return t.v;
}

// ---------------- LayerNorm: one wave per row of 768, fp32 in -> bf16 out ----
__global__ __launch_bounds__(256)
void ln_kernel(const float* __restrict__ x, const float* __restrict__ gam,
               const float* __restrict__ bet, unsigned short* __restrict__ out) {
  const int w = threadIdx.x >> 6, lane = threadIdx.x & 63;
  const size_t row = (size_t)blockIdx.x * 4 + w;
  const float* xr = x + row * D_MODEL;
  f32x4 v[3];
#pragma unroll
  for (int c = 0; c < 3; ++c) v[c] = *(const f32x4*)(xr + c * 256 + lane * 4);
  float s = 0.f;
#pragma unroll
  for (int c = 0; c < 3; ++c)
#pragma unroll
    for (int j = 0; j < 4; ++j) s += v[c][j];
#pragma unroll
  for (int o = 32; o; o >>= 1) s += __shfl_xor(s, o);
  const float mu = s * (1.0f / D_MODEL);
  float vs = 0.f;
#pragma unroll
  for (int c = 0; c < 3; ++c)
#pragma unroll
    for (int j = 0; j < 4; ++j) { float d = v[c][j] - mu; vs += d * d; }
#pragma unroll
  for (int o = 32; o; o >>= 1) vs += __shfl_xor(vs, o);
  const float rs = rsqrtf(vs * (1.0f / D_MODEL) + 1e-5f);
  unsigned short* orow = out + row * D_MODEL;
#pragma unroll
  for (int c = 0; c < 3; ++c) {
    us4 o4;
#pragma unroll
    for (int j = 0; j < 4; ++j) {
      int idx = c * 256 + lane * 4 + j;
      o4[j] = f2bf((v[c][j] - mu) * rs * gam[idx] + bet[idx]);
    }
    *(us4*)(orow + c * 256 + lane * 4) = o4;
  }
}

// ------------- weight transpose + cast: W[K][Nc] f32 -> Wt[Nc][K] bf16 -------
__global__ __launch_bounds__(256)
void wtrans_kernel(const float* __restrict__ W, unsigned short* __restrict__ Wt,
                   int K, int Nc) {
  __shared__ float t[32][33];
  const int tx = threadIdx.x & 31, ty = threadIdx.x >> 5;  // 32x8
  const int nb = blockIdx.x * 32, kb = blockIdx.y * 32;
#pragma unroll
  for (int i = 0; i < 4; ++i)
    t[ty + 8 * i][tx] = W[(size_t)(kb + ty + 8 * i) * Nc + nb + tx];
  __syncthreads();
#pragma unroll
  for (int i = 0; i < 4; ++i)
    Wt[(size_t)(nb + ty + 8 * i) * K + kb + tx] = f2bf(t[tx][ty + 8 * i]);
}

// ------ bias reshape: rel[H][N][N] f32 -> biasF bf16 in S^T-fragment order,
// PRE-SCALED by log2(e) (softmax runs in log2 domain). Lane l: q = qt*32+(l&31);
// reg r: k = kt*32 + (r&3) + 8*(r>>2) + 4*(l>>5). Packed (r0,r1)(r2,r3)..
__global__ __launch_bounds__(256)
void brelayout_kernel(const float* __restrict__ rel, unsigned short* __restrict__ bF) {
  const int gw = blockIdx.x * 4 + (threadIdx.x >> 6);  // (h*32+qt)*32+ktg
  const int lane = threadIdx.x & 63;
  const int ktg = gw & 31, qt = (gw >> 5) & 31, h = gw >> 10;
  const int q = qt * 32 + (lane & 31), hi = lane >> 5;
  const float* src = rel + ((size_t)h * SEQ + q) * SEQ + ktg * 32 + 4 * hi;
  const float L2E = 1.4426950408889634f;
  unsigned ow[8];
#pragma unroll
  for (int g = 0; g < 4; ++g) {
    f32x4 v = *(const f32x4*)(src + g * 8);
    asm("v_cvt_pk_bf16_f32 %0, %1, %2" : "=v"(ow[2 * g])     : "v"(v[0] * L2E), "v"(v[1] * L2E));
    asm("v_cvt_pk_bf16_f32 %0, %1, %2" : "=v"(ow[2 * g + 1]) : "v"(v[2] * L2E), "v"(v[3] * L2E));
  }
  unsigned short* dst = bF + (((size_t)gw) * 64 + lane) * 16;
  *(uint4*)(dst)     = make_uint4(ow[0], ow[1], ow[2], ow[3]);
  *(uint4*)(dst + 8) = make_uint4(ow[4], ow[5], ow[6], ow[7]);
}

// -------- GEMM: C[M][N] = A[M][K] @ Bt[N][K]^T, bf16, fused epilogue --------
// 128x128 tile, BK=64, 4 waves (wave tile 64x64 = 2x2 of 32x32x16 MFMA).
// LDS XOR-swizzle on the per-lane GLOBAL source (gload dest linear) + ds_read.
#define MODE_QKV  0
#define MODE_PROJ 1
#define MODE_FFN1 2
#define MODE_FFN2 3

template <int MODE>
__global__ __launch_bounds__(256)
void gemm_bt(const unsigned short* __restrict__ A, const unsigned short* __restrict__ Bt,
             int K, const float* __restrict__ bias, const float* __restrict__ resid,
             float* __restrict__ outF, unsigned short* __restrict__ o0,
             unsigned short* __restrict__ o1, unsigned short* __restrict__ o2) {
  __shared__ alignas(16) unsigned short smem[2][2][128 * 64];  // [A/B][buf][tile]
  const int tid = threadIdx.x;
  const int w = tid >> 6, lane = tid & 63;
  const int l31 = lane & 31, hi = lane >> 5;
  const int wm = w >> 1, wn = w & 1;
  // XCD-chunked bijective swizzle (all grids are multiples of 8 blocks)
  const int nwg = gridDim.x * gridDim.y;
  const int bid0 = blockIdx.y * gridDim.x + blockIdx.x;
  const int cpx = nwg >> 3;
  const int bid = (bid0 & 7) * cpx + (bid0 >> 3);
  const int bx = bid % gridDim.x, by = bid / gridDim.x;
  const size_t m0 = (size_t)by * 128;
  const size_t n0 = (size_t)bx * 128;
  const unsigned short* gA = A + m0 * K;
  const unsigned short* gB = Bt + n0 * K;

  // staging decomposition: lane -> (row-in-8-group, 16B unit), source col XOR'd
  const int r8 = lane >> 3;         // 0..7
  const int u8 = lane & 7;          // 16B unit 0..7 within 128B row
  const int ucol = (u8 ^ r8) * 8;   // swizzled element offset within BK=64 row

  f32x16 acc[2][2];
#pragma unroll
  for (int i = 0; i < 2; ++i)
#pragma unroll
    for (int j = 0; j < 2; ++j) acc[i][j] = (f32x16)(0.f);
  const int nk = K >> 6;

  auto stage = [&](int buf, int kt) {
#pragma unroll
    for (int g = 0; g < 4; ++g) {
      const int rowb = w * 32 + g * 8;  // wave-uniform base row (multiple of 8)
      gload_lds16(gA + (size_t)(rowb + r8) * K + kt * 64 + ucol, &smem[0][buf][rowb * 64]);
      gload_lds16(gB + (size_t)(rowb + r8) * K + kt * 64 + ucol, &smem[1][buf][rowb * 64]);
    }
  };

  // frag read offsets: row = base + l31 (base % 8 == 0), unit j = ks*2 + hi
  const int swr = l31 & 7;
  const int rA = (wm * 64 + l31) * 64;
  const int rB = (wn * 64 + l31) * 64;

  stage(0, 0);
  __syncthreads();
  for (int kt = 0; kt < nk; ++kt) {
    const int buf = kt & 1;
    if (kt + 1 < nk) stage(buf ^ 1, kt + 1);
    bf16x8 af[2][4], bf[2][4];
#pragma unroll
    for (int mt = 0; mt < 2; ++mt)
#pragma unroll
      for (int ks = 0; ks < 4; ++ks) {
        af[mt][ks] = *(const bf16x8*)&smem[0][buf][rA + mt * 2048 + (((ks * 2 + hi) ^ swr) * 8)];
        bf[mt][ks] = *(const bf16x8*)&smem[1][buf][rB + mt * 2048 + (((ks * 2 + hi) ^ swr) * 8)];
      }
#pragma unroll
    for (int mt = 0; mt < 2; ++mt)
#pragma unroll
      for (int nt = 0; nt < 2; ++nt)
#pragma unroll
        for (int ks = 0; ks < 4; ++ks)
          acc[mt][nt] = mfma32(af[mt][ks], bf[nt][ks], acc[mt][nt]);
    __syncthreads();   // staging of buf^1 complete + all waves done reading buf
  }

  // ---- V-region of QKV: transpose through (now dead) LDS, coalesced stores
  if constexpr (MODE == MODE_QKV) {
    if (bx >= 12) {
      unsigned short* tb = &smem[0][0][0];  // [128 n][136 m] (pad: 16B rows, banks ok)
#pragma unroll
      for (int mt = 0; mt < 2; ++mt)
#pragma unroll
        for (int nt = 0; nt < 2; ++nt)
#pragma unroll
          for (int r = 0; r < 16; ++r) {
            const int nl = wn * 64 + nt * 32 + l31;
            const int ml = wm * 64 + mt * 32 + (r & 3) + 8 * (r >> 2) + 4 * hi;
            tb[nl * 136 + ml] = f2bf(acc[mt][nt][r] + bias[(int)n0 + nl]);
          }
      __syncthreads();
      const int rr = tid & 127, half = tid >> 7;
      const int n2 = ((int)n0 - 1536) + rr;
      const int hh = n2 >> 6, dh = n2 & 63;
      const int b2 = (int)(m0 >> 10), nq0 = (int)(m0 & 1023);
      unsigned short* dst = o2 + ((size_t)(b2 * NH + hh) * DHD + dh) * SEQ + nq0 + half * 64;
      const unsigned short* src = tb + rr * 136 + half * 64;
#pragma unroll
      for (int i = 0; i < 4; ++i)
        *(uint4*)(dst + i * 8) = *(const uint4*)(src + i * 8);
      return;
    }
  }

  // epilogue: 32x32 C/D map: n = tile + l31, m = tile + (r&3) + 8*(r>>2) + 4*hi
#pragma unroll
  for (int mt = 0; mt < 2; ++mt) {
#pragma unroll
    for (int nt = 0; nt < 2; ++nt) {
#pragma unroll
      for (int r = 0; r < 16; ++r) {
        const int m = (int)m0 + wm * 64 + mt * 32 + (r & 3) + 8 * (r >> 2) + 4 * hi;
        const int n = (int)n0 + wn * 64 + nt * 32 + l31;
        float v = acc[mt][nt][r] + bias[n];
        if constexpr (MODE == MODE_QKV) {
          const int b = m >> 10, nq = m & 1023;
          if (n < 768) {
            // Q: pre-scale by 0.125*log2(e) (softmax runs in log2 domain)
            const int h = n >> 6, dh = n & 63;
            o0[(((size_t)(b * NH + h)) * SEQ + nq) * DHD + dh] =
                f2bf(v * 0.1803368801111244f);
          } else {
            const int n2 = n - 768, h = n2 >> 6, dh = n2 & 63;
            o1[(((size_t)(b * NH + h)) * SEQ + nq) * DHD + dh] = f2bf(v);
          }
        } else if constexpr (MODE == MODE_PROJ) {
          const size_t off = (size_t)m * D_MODEL + n;
          outF[off] = v + resid[off];
        } else if constexpr (MODE == MODE_FFN1) {
          // gelu(v) = 0.5v(1+tanh(u)) == v * sigmoid(2u), u=0.79788456(v+0.044715v^3)
          const float e = __expf(-1.5957691216057308f * (v + 0.044715f * v * v * v));
          o0[(size_t)m * DFF + n] = f2bf(v / (1.0f + e));
        } else {  // FFN2: in-place residual on outF (x2 lives there)
          const size_t off = (size_t)m * D_MODEL + n;
          outF[off] = v + resid[off];
        }
      }
    }
  }
}

// ------- fused flash attention: 4 waves x 32 q-rows, 32x32x16 MFMA ----------
// K/V staged into LDS in fragment order (shared by all 4 waves); swapped
// operands: S^T[k][q] = mfma(K,Q) so q = lane&31, k = reg-mapped. Softmax in
// log2 domain (Q pre-scaled, biasF pre-scaled, exp2), fully in-lane with
// defer-max. P -> PV B-frags entirely in-register via cvt_pk + permlane32_swap.
__global__ __launch_bounds__(256, 4)
void attn_kernel(const unsigned short* __restrict__ q, const unsigned short* __restrict__ k,
                 const unsigned short* __restrict__ vt, const unsigned short* __restrict__ bF,
                 unsigned short* __restrict__ ctx) {
  // kv slots: [buf][slot 0..15][64 lanes * 8 shorts]; slots 0-7 = K (kt*4+ds),
  // slots 8-15 = V (8 + dt*4 + kh). Each slot = one ds_read_b128 fragment set.
  __shared__ alignas(16) unsigned short kv[2][16][64 * 8];
  const int tid = threadIdx.x, w = tid >> 6, lane = tid & 63;
  const int l31 = lane & 31, hi = lane >> 5;
  // XCD-chunked swizzle (768 % 8 == 0 -> bijective): 12 bh per XCD, K/V L2-res.
  const int bid = (blockIdx.x & 7) * 96 + (blockIdx.x >> 3);
  const int bh = bid >> 3, qblk = bid & 7;
  const int b = bh / NH, h = bh % NH;
  const int q0w = qblk * 128 + w * 32;
  const unsigned short* qp = q + (size_t)bh * SEQ * DHD;
  const unsigned short* kp = k + (size_t)bh * SEQ * DHD;
  const unsigned short* vp = vt + (size_t)bh * DHD * SEQ;
  // bias fragment stream for this wave's 32 q-rows (qt = qblk*4 + w)
  const unsigned short* bfp = bF + ((((size_t)(h * 32 + qblk * 4 + w)) * 32) * 64 + lane) * 16;

  // Q B-fragments (kept all kernel): col q = l31, d = ds*16 + hi*8 + e
  bf16x8 Qf[4];
#pragma unroll
  for (int ds = 0; ds < 4; ++ds)
    Qf[ds] = *(const bf16x8*)(qp + (size_t)(q0w + l31) * DHD + ds * 16 + hi * 8);

  f32x16 o[2];
#pragma unroll
  for (int dt = 0; dt < 2; ++dt) o[dt] = (f32x16)(0.f);
  float mrun = -INFINITY, lrun = 0.f;  // log2-domain running max / sum

  auto stage = [&](int buf, int kb) {
    if (w < 2) {  // K slots: kt = w, ds 0..3; lane = A-frag row k, cols d
      const unsigned short* g0 = kp + (size_t)(kb * 64 + w * 32 + l31) * DHD + hi * 8;
#pragma unroll
      for (int ds = 0; ds < 4; ++ds)
        gload_lds16(g0 + ds * 16, &kv[buf][w * 4 + ds][0]);
    } else {      // V slots: dt = w-2, kh 0..3; lane = A-frag row d, cols k
      const int dt = w - 2;
      const unsigned short* g0 = vp + (size_t)(dt * 32 + l31) * SEQ + kb * 64 + hi * 8;
#pragma unroll
      for (int kh = 0; kh < 4; ++kh)
        gload_lds16(g0 + kh * 16, &kv[buf][8 + dt * 4 + kh][0]);
    }
  };

  stage(0, 0);
  __syncthreads();
  for (int kb = 0; kb < SEQ / 64; ++kb) {
    const int buf = kb & 1;
    if (kb + 1 < SEQ / 64) stage(buf ^ 1, kb + 1);

    // ---- S^T for 64 keys: 2 kt-tiles x 4 d-slices
    f32x16 s0 = (f32x16)(0.f), s1 = (f32x16)(0.f);
    __builtin_amdgcn_s_setprio(1);
#pragma unroll
    for (int ds = 0; ds < 4; ++ds) {
      bf16x8 kf0 = *(const bf16x8*)&kv[buf][ds][lane * 8];
      s0 = mfma32(kf0, Qf[ds], s0);
      bf16x8 kf1 = *(const bf16x8*)&kv[buf][4 + ds][lane * 8];
      s1 = mfma32(kf1, Qf[ds], s1);
    }
    __builtin_amdgcn_s_setprio(0);

    // ---- bias add (bf16 fragment stream, log2 domain; Q already scaled)
    const unsigned short* bb = bfp + (size_t)(kb * 2) * 64 * 16;
    uint4 a0 = *(const uint4*)(bb),            a1 = *(const uint4*)(bb + 8);
    uint4 c0 = *(const uint4*)(bb + 64 * 16),  c1 = *(const uint4*)(bb + 64 * 16 + 8);
    unsigned uw0[8] = {a0.x, a0.y, a0.z, a0.w, a1.x, a1.y, a1.z, a1.w};
    unsigned uw1[8] = {c0.x, c0.y, c0.z, c0.w, c1.x, c1.y, c1.z, c1.w};
    float p0[16], p1[16];
#pragma unroll
    for (int j = 0; j < 8; ++j) {
      p0[2 * j]     = s0[2 * j]     + __uint_as_float(uw0[j] << 16);
      p0[2 * j + 1] = s0[2 * j + 1] + __uint_as_float(uw0[j] & 0xffff0000u);
      p1[2 * j]     = s1[2 * j]     + __uint_as_float(uw1[j] << 16);
      p1[2 * j + 1] = s1[2 * j + 1] + __uint_as_float(uw1[j] & 0xffff0000u);
    }

    // ---- softmax (defer-max, log2 domain): THR = 11 (~= 7.6 nats)
    float pmax = p0[0];
#pragma unroll
    for (int i = 1; i < 16; ++i) pmax = fmaxf(pmax, p0[i]);
#pragma unroll
    for (int i = 0; i < 16; ++i) pmax = fmaxf(pmax, p1[i]);
    if (!__all(pmax - mrun <= 11.0f)) {
      float pm = fmaxf(pmax, __shfl_xor(pmax, 32));
      const float mn = fmaxf(mrun, pm);
      const float al = __builtin_amdgcn_exp2f(mrun - mn);
      mrun = mn;
      lrun *= al;
#pragma unroll
      for (int dt = 0; dt < 2; ++dt)
#pragma unroll
        for (int r = 0; r < 16; ++r) o[dt][r] *= al;
    }
#pragma unroll
    for (int i = 0; i < 16; ++i) { p0[i] = __builtin_amdgcn_exp2f(p0[i] - mrun); lrun += p0[i]; }
#pragma unroll
    for (int i = 0; i < 16; ++i) { p1[i] = __builtin_amdgcn_exp2f(p1[i] - mrun); lrun += p1[i]; }

    // ---- pack P -> bf16 pairs; permlane32_swap assembles PV B-frags in-reg.
    // Lane(hi) holds k = (r&3)+8*(r>>2)+4*hi; pair word g covers k-quad
    // {g*8+4*hi .. +3}. swap(word g, word g+2) yields frag words for both
    // halves: pf[t] element e covers k = t*16 + hi*8 + e.  (verified map)
    unsigned wpk[16];
#pragma unroll
    for (int i = 0; i < 8; ++i) {
      asm("v_cvt_pk_bf16_f32 %0, %1, %2" : "=v"(wpk[i])     : "v"(p0[2 * i]), "v"(p0[2 * i + 1]));
      asm("v_cvt_pk_bf16_f32 %0, %1, %2" : "=v"(wpk[8 + i]) : "v"(p1[2 * i]), "v"(p1[2 * i + 1]));
    }
    plswap(wpk[0], wpk[2]);   plswap(wpk[1], wpk[3]);
    plswap(wpk[4], wpk[6]);   plswap(wpk[5], wpk[7]);
    plswap(wpk[8], wpk[10]);  plswap(wpk[9], wpk[11]);
    plswap(wpk[12], wpk[14]); plswap(wpk[13], wpk[15]);
    bf16x8 pf[4];
    pf[0] = mk8(wpk[0], wpk[1], wpk[2], wpk[3]);
    pf[1] = mk8(wpk[4], wpk[5], wpk[6], wpk[7]);
    pf[2] = mk8(wpk[8], wpk[9], wpk[10], wpk[11]);
    pf[3] = mk8(wpk[12], wpk[13], wpk[14], wpk[15]);

    // ---- PV: O^T[d][q] += V^T-frag x P-frag
    __builtin_amdgcn_s_setprio(1);
#pragma unroll
    for (int dt = 0; dt < 2; ++dt)
#pragma unroll
      for (int kh = 0; kh < 4; ++kh) {
        bf16x8 vf = *(const bf16x8*)&kv[buf][8 + dt * 4 + kh][lane * 8];
        o[dt] = mfma32(vf, pf[kh], o[dt]);
      }
    __builtin_amdgcn_s_setprio(0);

    __syncthreads();  // staging of buf^1 complete + all waves done with buf
  }

  lrun += __shfl_xor(lrun, 32);
  const float inv = 1.0f / lrun;
  // O^T reg r: d = dt*32 + (r&3) + 8*(r>>2) + 4*hi, q = l31
  unsigned short* crow = ctx + ((size_t)b * SEQ + q0w + l31) * D_MODEL + h * DHD;
#pragma unroll
  for (int dt = 0; dt < 2; ++dt)
#pragma unroll
    for (int g = 0; g < 4; ++g) {
      us4 ov;
#pragma unroll
      for (int j = 0; j < 4; ++j) ov[j] = f2bf(o[dt][4 * g + j] * inv);
      *(us4*)(crow + dt * 32 + g * 8 + 4 * hi) = ov;
    }
}

// ----------------------------------------------------------------------------
extern "C" void kernel_launch(void* const* d_in, const int* in_sizes, int n_in,
                              void* d_out, int out_size, void* d_ws, size_t ws_size,
                              hipStream_t stream) {
  (void)in_sizes; (void)n_in; (void)out_size; (void)ws_size;
  const float* x     = (const float*)d_in[0];
  const float* ln1_g = (const float*)d_in[1];
  const float* ln1_b = (const float*)d_in[2];
  const float* wqkv  = (const float*)d_in[3];
  const float* bqkv  = (const float*)d_in[4];
  const float* wo    = (const float*)d_in[5];
  const float* bo    = (const float*)d_in[6];
  const float* rel   = (const float*)d_in[7];
  const float* ln2_g = (const float*)d_in[8];
  const float* ln2_b = (const float*)d_in[9];
  const float* w1    = (const float*)d_in[10];
  const float* b1    = (const float*)d_in[11];
  const float* w2    = (const float*)d_in[12];
  const float* b2    = (const float*)d_in[13];
  float* out = (float*)d_out;

  char* p = (char*)d_ws;
  auto take = [&](size_t bytes) {
    void* r = (void*)p;
    p += (bytes + 255) & ~(size_t)255;
    return r;
  };
  unsigned short* hbuf  = (unsigned short*)take((size_t)NTOK * D_MODEL * 2);
  unsigned short* wqkvT = (unsigned short*)take((size_t)2304 * 768 * 2);
  unsigned short* woT   = (unsigned short*)take((size_t)768 * 768 * 2);
  unsigned short* w1T   = (unsigned short*)take((size_t)3072 * 768 * 2);
  unsigned short* w2T   = (unsigned short*)take((size_t)768 * 3072 * 2);
  unsigned short* qbuf  = (unsigned short*)take((size_t)8 * NH * SEQ * DHD * 2);
  unsigned short* kbuf  = (unsigned short*)take((size_t)8 * NH * SEQ * DHD * 2);
  unsigned short* vtbuf = (unsigned short*)take((size_t)8 * NH * SEQ * DHD * 2);
  unsigned short* ctxb  = (unsigned short*)take((size_t)NTOK * D_MODEL * 2);
  unsigned short* h1buf = (unsigned short*)take((size_t)NTOK * DFF * 2);
  // biasF (25.2 MB) aliases h1buf (50.3 MB): dead before FFN1 writes h1buf.
  unsigned short* biasF = h1buf;
  // x2 (post-attention residual stream) lives in d_out (fp32).

  // weight prep (independent of activations)
  wtrans_kernel<<<dim3(2304 / 32, 768 / 32), 256, 0, stream>>>(wqkv, wqkvT, 768, 2304);
  wtrans_kernel<<<dim3(768 / 32, 768 / 32), 256, 0, stream>>>(wo, woT, 768, 768);
  wtrans_kernel<<<dim3(3072 / 32, 768 / 32), 256, 0, stream>>>(w1, w1T, 768, 3072);
  wtrans_kernel<<<dim3(768 / 32, 3072 / 32), 256, 0, stream>>>(w2, w2T, 3072, 768);
  // bias -> bf16 fragment order (pre-scaled by log2 e)
  brelayout_kernel<<<NH * 32 * 32 / 4, 256, 0, stream>>>(rel, biasF);

  // LN1: x -> h (bf16)
  ln_kernel<<<NTOK / 4, 256, 0, stream>>>(x, ln1_g, ln1_b, hbuf);
  // QKV: h @ wqkv + bqkv -> q (pre-scaled), k, Vt (bf16, attention layouts)
  gemm_bt<MODE_QKV><<<dim3(2304 / 128, NTOK / 128), 256, 0, stream>>>(
      hbuf, wqkvT, 768, bqkv, nullptr, nullptr, qbuf, kbuf, vtbuf);
  // attention -> ctx (bf16, [tok][D])
  attn_kernel<<<8 * NH * (SEQ / 128), 256, 0, stream>>>(qbuf, kbuf, vtbuf, biasF, ctxb);
  // proj: ctx @ wo + bo + x -> x2 (fp32, in d_out)
  gemm_bt<MODE_PROJ><<<dim3(768 / 128, NTOK / 128), 256, 0, stream>>>(
      ctxb, woT, 768, bo, x, out, nullptr, nullptr, nullptr);
  // LN2: x2 -> h2 (bf16, reuse hbuf)
  ln_kernel<<<NTOK / 4, 256, 0, stream>>>(out, ln2_g, ln2_b, hbuf);
  // FFN1: h2 @ w1 + b1, gelu -> h1 (bf16)
  gemm_bt<MODE_FFN1><<<dim3(DFF / 128, NTOK / 128), 256, 0, stream>>>(
      hbuf, w1T, 768, b1, nullptr, nullptr, h1buf, nullptr, nullptr);
  // FFN2: h1 @ w2 + b2 + x2 -> out (fp32, in place on d_out)
  gemm_bt<MODE_FFN2><<<dim3(768 / 128, NTOK / 128), 256, 0, stream>>>(
      h1buf, w2T, 3072, b2, out, out, nullptr, nullptr, nullptr);
}